// Round 1
// baseline (1774.398 us; speedup 1.0000x reference)
//
#include <hip/hip_runtime.h>
#include <cmath>

#define CC 128
#define HH 64
#define WWI 64
#define HR 32
#define LL 1024
#define NB 16

// per-batch workspace floats: b_dsT + f_dsT + n2 + bnorm + valid + bufA + bufB
#define PB_FLOATS (2*LL*CC + 3*LL + 2*LL*LL)

#define BM 128
#define BN 128
#define BK 16

// ---- downsample + transpose to (batch, pixel, channel) layout ----
__global__ __launch_bounds__(256) void k_prep(const float* __restrict__ f_o,
                                              const float* __restrict__ b_o,
                                              float* __restrict__ f_dsT,
                                              float* __restrict__ b_dsT,
                                              int b0) {
    int t = blockIdx.x * 256 + threadIdx.x;     // Gc*1024*128 threads
    int c  = t & 127;
    int u  = (t >> 7) & (LL - 1);
    int bz = t >> 17;
    int gb = b0 + bz;
    int uy = u >> 5, ux = u & 31;
    size_t src = ((size_t)(gb * CC + c) * HH + 2 * uy) * WWI + 2 * ux;
    size_t dst = ((size_t)bz * LL + u) * CC + c;
    f_dsT[dst] = f_o[src];
    b_dsT[dst] = b_o[src];
}

// ---- per-pixel sum of squares of downsampled b ----
__global__ __launch_bounds__(256) void k_n2(const float* __restrict__ b_dsT,
                                            float* __restrict__ n2) {
    int t = blockIdx.x * 256 + threadIdx.x;     // Gc*1024 threads (bz*L+u)
    const float4* row = (const float4*)(b_dsT + (size_t)t * CC);
    float s = 0.f;
#pragma unroll
    for (int i = 0; i < 32; i++) {
        float4 v = row[i];
        s += v.x * v.x + v.y * v.y + v.z * v.z + v.w * v.w;
    }
    n2[t] = s;
}

// ---- bnorm (3x3 box-sum of n2, sqrt, clamp) and valid mask ----
__global__ __launch_bounds__(256) void k_bnorm_valid(const float* __restrict__ n2,
                                                     const float* __restrict__ mask,
                                                     float* __restrict__ bnorm,
                                                     float* __restrict__ valid,
                                                     int b0) {
    int t = blockIdx.x * 256 + threadIdx.x;     // Gc*1024 threads
    int p  = t & (LL - 1);
    int bz = t >> 10;
    int gb = b0 + bz;
    int py = p >> 5, px = p & 31;
    const float* mb = mask + (size_t)gb * HH * WWI;
    float s = 0.f, msum = 0.f;
#pragma unroll
    for (int dy = -1; dy <= 1; dy++) {
#pragma unroll
        for (int dx = -1; dx <= 1; dx++) {
            int py2 = py + dy, px2 = px + dx;
            if ((unsigned)py2 < 32u && (unsigned)px2 < 32u) {
                s    += n2[bz * LL + ((py2 << 5) | px2)];
                msum += mb[(2 * py2) * WWI + 2 * px2];
            }
        }
    }
    bnorm[t] = fmaxf(sqrtf(s), 1e-4f);
    valid[t] = (msum == 0.0f) ? 1.0f : 0.0f;
}

// ---- T[u,v] = sum_c b_ds[u,c] * f_ds[v,c]  (M=N=1024, K=128) ----
__global__ __launch_bounds__(256) void k_gemm_T(const float* __restrict__ A,
                                                const float* __restrict__ B,
                                                float* __restrict__ Tout) {
    int bz = blockIdx.z;
    const float* Ab = A + (size_t)bz * LL * CC;
    const float* Bb = B + (size_t)bz * LL * CC;
    float* Tb = Tout + (size_t)bz * LL * LL;
    int m0 = blockIdx.y * BM, n0 = blockIdx.x * BN;
    __shared__ __align__(16) float As[BK][BM + 4];
    __shared__ __align__(16) float Bs[BK][BN + 4];
    int t = threadIdx.x;
    int kl = t & 15, rl = t >> 4;
    int tx = t & 15, ty = t >> 4;
    float acc[8][8] = {};
    for (int k0 = 0; k0 < CC; k0 += BK) {
#pragma unroll
        for (int i = 0; i < 8; i++) {
            int rr = rl + 16 * i;
            As[kl][rr] = Ab[(size_t)(m0 + rr) * CC + k0 + kl];
            Bs[kl][rr] = Bb[(size_t)(n0 + rr) * CC + k0 + kl];
        }
        __syncthreads();
#pragma unroll
        for (int k = 0; k < BK; k++) {
            float4 a0 = *(const float4*)&As[k][ty * 8];
            float4 a1 = *(const float4*)&As[k][ty * 8 + 4];
            float4 b0 = *(const float4*)&Bs[k][tx * 8];
            float4 b1 = *(const float4*)&Bs[k][tx * 8 + 4];
            float a[8] = {a0.x, a0.y, a0.z, a0.w, a1.x, a1.y, a1.z, a1.w};
            float b[8] = {b0.x, b0.y, b0.z, b0.w, b1.x, b1.y, b1.z, b1.w};
#pragma unroll
            for (int i = 0; i < 8; i++)
#pragma unroll
                for (int j = 0; j < 8; j++)
                    acc[i][j] = fmaf(a[i], b[j], acc[i][j]);
        }
        __syncthreads();
    }
#pragma unroll
    for (int i = 0; i < 8; i++) {
        float* dst = Tb + (size_t)(m0 + ty * 8 + i) * LL + n0 + tx * 8;
        float4 v0 = {acc[i][0], acc[i][1], acc[i][2], acc[i][3]};
        float4 v1 = {acc[i][4], acc[i][5], acc[i][6], acc[i][7]};
        *(float4*)dst = v0;
        *(float4*)(dst + 4) = v1;
    }
}

// ---- S_raw[p,q] = (sum_{dy,dx} T[p+d, q+d]) / bnorm[p]  (2D bounds) ----
__global__ __launch_bounds__(256) void k_st1(const float* __restrict__ Tm,
                                             const float* __restrict__ bnorm,
                                             float* __restrict__ outp) {
    int bz = blockIdx.z;
    int p  = blockIdx.x;
    const float* Tb = Tm + (size_t)bz * LL * LL;
    float inv = 1.0f / bnorm[bz * LL + p];
    float* ob = outp + (size_t)bz * LL * LL + (size_t)p * LL;
    int py = p >> 5, px = p & 31;
    for (int q = threadIdx.x; q < LL; q += 256) {
        int qy = q >> 5, qx = q & 31;
        float acc = 0.f;
#pragma unroll
        for (int dy = -1; dy <= 1; dy++) {
#pragma unroll
            for (int dx = -1; dx <= 1; dx++) {
                int py2 = py + dy, px2 = px + dx, qy2 = qy + dy, qx2 = qx + dx;
                if ((unsigned)py2 < 32u && (unsigned)px2 < 32u &&
                    (unsigned)qy2 < 32u && (unsigned)qx2 < 32u)
                    acc += Tb[(size_t)((py2 << 5) | px2) * LL + ((qy2 << 5) | qx2)];
            }
        }
        ob[q] = acc * inv;
    }
}

// ---- first diag_fuse, flat-index space (matches reference wrap semantics) ----
__global__ __launch_bounds__(256) void k_st2(const float* __restrict__ in,
                                             float* __restrict__ outp) {
    int bz = blockIdx.z;
    int i  = blockIdx.x;
    const float* ib = in + (size_t)bz * LL * LL;
    float* ob = outp + (size_t)bz * LL * LL + (size_t)i * LL;
    for (int j = threadIdx.x; j < LL; j += 256) {
        float acc = 0.f;
#pragma unroll
        for (int k = -1; k <= 1; k++) {
            int ii = i + k, jj = j + k;
            if ((unsigned)ii < 1024u && (unsigned)jj < 1024u)
                acc += ib[(size_t)ii * LL + jj];
        }
        ob[j] = acc;
    }
}

// ---- second diag_fuse in sigma-space: sigma(t) = (t&31)*32 + (t>>5) ----
__global__ __launch_bounds__(256) void k_st3(const float* __restrict__ in,
                                             float* __restrict__ outp) {
    int bz = blockIdx.z;
    int p  = blockIdx.x;
    const float* ib = in + (size_t)bz * LL * LL;
    float* ob = outp + (size_t)bz * LL * LL + (size_t)p * LL;
    int sp = ((p & 31) << 5) | (p >> 5);
    int rowv[3], rows[3];
#pragma unroll
    for (int k = 0; k < 3; k++) {
        int tp = sp + k - 1;
        rowv[k] = ((unsigned)tp < 1024u) ? 1 : 0;
        rows[k] = ((tp & 31) << 5) | ((tp >> 5) & 31);
    }
    for (int j = threadIdx.x; j < LL; j += 256) {
        int sq = ((j & 31) << 5) | (j >> 5);
        float acc = 0.f;
#pragma unroll
        for (int k = 0; k < 3; k++) {
            int tq = sq + k - 1;
            if (rowv[k] && (unsigned)tq < 1024u) {
                int col = ((tq & 31) << 5) | (tq >> 5);
                acc += ib[(size_t)rows[k] * LL + col];
            }
        }
        ob[j] = acc;
    }
}

// ---- column-wise (over p) softmax with valid masking, scale 10 ----
__global__ __launch_bounds__(256) void k_softmax(const float* __restrict__ S,
                                                 const float* __restrict__ valid,
                                                 float* __restrict__ outS) {
    int bz = blockIdx.z;
    const float* Sb = S + (size_t)bz * LL * LL;
    const float* vb = valid + bz * LL;
    float* ob = outS + (size_t)bz * LL * LL;
    int lq = threadIdx.x & 63;
    int st = threadIdx.x >> 6;
    int q  = blockIdx.x * 64 + lq;
    __shared__ float red[4][64];
    float m = -1e30f;
    for (int p = st; p < LL; p += 4)
        m = fmaxf(m, Sb[(size_t)p * LL + q] * vb[p]);
    red[st][lq] = m;
    __syncthreads();
    m = fmaxf(fmaxf(red[0][lq], red[1][lq]), fmaxf(red[2][lq], red[3][lq]));
    __syncthreads();
    float s = 0.f;
    for (int p = st; p < LL; p += 4)
        s += __expf(10.f * (Sb[(size_t)p * LL + q] * vb[p] - m));
    red[st][lq] = s;
    __syncthreads();
    s = red[0][lq] + red[1][lq] + red[2][lq] + red[3][lq];
    float inv = 1.0f / s;
    for (int p = st; p < LL; p += 4) {
        float vl = vb[p];
        ob[(size_t)p * LL + q] = __expf(10.f * (Sb[(size_t)p * LL + q] * vl - m)) * inv * vl;
    }
}

// ---- W GEMM + fused scatter epilogue:
//  W[m=(c,iy,ix), n=q] = sum_p b_o[c, 2py+iy-1, 2px+ix-1] * score[p, q]
//  each W element adds 0.25*W to out[c, 2y+iy-1, 2x+ix-1] (exactly one target)
__global__ __launch_bounds__(256) void k_gemm_W(const float* __restrict__ b_o,
                                                const float* __restrict__ score,
                                                float* __restrict__ outp,
                                                int b0) {
    int bz = blockIdx.z, gb = b0 + bz;
    const float* sc = score + (size_t)bz * LL * LL;
    int m0 = blockIdx.y * BM, n0 = blockIdx.x * BN;  // M=1152 (9 tiles), N=1024 (8 tiles)
    __shared__ __align__(16) float As[BK][BM + 4];
    __shared__ __align__(16) float Bs[BK][BN + 4];
    int t = threadIdx.x;
    int ml = t & 127, pl = t >> 7;
    int gm = m0 + ml;
    int c = gm / 9, rem = gm - 9 * c, iy = rem / 3, ix = rem - 3 * iy;
    const float* bb = b_o + (size_t)(gb * CC + c) * HH * WWI;
    int tx = t & 15, ty = t >> 4;
    float acc[8][8] = {};
    for (int k0 = 0; k0 < LL; k0 += BK) {
#pragma unroll
        for (int i = 0; i < 8; i++) {
            int pp = pl + 2 * i;
            int p  = k0 + pp;
            int row = 2 * (p >> 5) + iy - 1;
            int col = 2 * (p & 31) + ix - 1;
            float v = 0.f;
            if ((unsigned)row < 64u && (unsigned)col < 64u) v = bb[row * WWI + col];
            As[pp][ml] = v;
            Bs[pp][ml] = sc[(size_t)p * LL + n0 + ml];
        }
        __syncthreads();
#pragma unroll
        for (int k = 0; k < BK; k++) {
            float4 a0 = *(const float4*)&As[k][ty * 8];
            float4 a1 = *(const float4*)&As[k][ty * 8 + 4];
            float4 b0 = *(const float4*)&Bs[k][tx * 8];
            float4 b1 = *(const float4*)&Bs[k][tx * 8 + 4];
            float a[8] = {a0.x, a0.y, a0.z, a0.w, a1.x, a1.y, a1.z, a1.w};
            float b[8] = {b0.x, b0.y, b0.z, b0.w, b1.x, b1.y, b1.z, b1.w};
#pragma unroll
            for (int i = 0; i < 8; i++)
#pragma unroll
                for (int j = 0; j < 8; j++)
                    acc[i][j] = fmaf(a[i], b[j], acc[i][j]);
        }
        __syncthreads();
    }
#pragma unroll
    for (int i = 0; i < 8; i++) {
        int m = m0 + ty * 8 + i;
        int c2 = m / 9, r2 = m - 9 * c2, jy = r2 / 3, jx = r2 - 3 * jy;
        float* ob = outp + (size_t)(gb * CC + c2) * HH * WWI;
#pragma unroll
        for (int j = 0; j < 8; j++) {
            int n  = n0 + tx * 8 + j;
            int oy = 2 * (n >> 5) + jy - 1;
            int ox = 2 * (n & 31) + jx - 1;
            if ((unsigned)oy < 64u && (unsigned)ox < 64u)
                atomicAdd(ob + oy * WWI + ox, 0.25f * acc[i][j]);
        }
    }
}

extern "C" void kernel_launch(void* const* d_in, const int* in_sizes, int n_in,
                              void* d_out, int out_size, void* d_ws, size_t ws_size,
                              hipStream_t stream) {
    (void)in_sizes; (void)n_in;
    const float* f_o  = (const float*)d_in[0];
    const float* b_o  = (const float*)d_in[1];
    const float* mask = (const float*)d_in[2];
    float* out = (float*)d_out;

    hipMemsetAsync(d_out, 0, (size_t)out_size * sizeof(float), stream);

    size_t pb_bytes = (size_t)PB_FLOATS * sizeof(float);   // ~9.45 MB per batch
    int G = (int)(ws_size / pb_bytes);
    if (G < 1) G = 1;
    if (G > NB) G = NB;

    float* ws    = (float*)d_ws;
    float* b_dsT = ws;
    float* f_dsT = b_dsT + (size_t)G * LL * CC;
    float* n2    = f_dsT + (size_t)G * LL * CC;
    float* bnorm = n2 + (size_t)G * LL;
    float* valid = bnorm + (size_t)G * LL;
    float* bufA  = valid + (size_t)G * LL;
    float* bufB  = bufA + (size_t)G * LL * LL;

    for (int b0 = 0; b0 < NB; b0 += G) {
        int Gc = NB - b0 < G ? NB - b0 : G;
        k_prep<<<dim3(Gc * 512), 256, 0, stream>>>(f_o, b_o, f_dsT, b_dsT, b0);
        k_n2<<<dim3(Gc * 4), 256, 0, stream>>>(b_dsT, n2);
        k_bnorm_valid<<<dim3(Gc * 4), 256, 0, stream>>>(n2, mask, bnorm, valid, b0);
        k_gemm_T<<<dim3(8, 8, Gc), 256, 0, stream>>>(b_dsT, f_dsT, bufA);
        k_st1<<<dim3(1024, 1, Gc), 256, 0, stream>>>(bufA, bnorm, bufB);
        k_st2<<<dim3(1024, 1, Gc), 256, 0, stream>>>(bufB, bufA);
        k_st3<<<dim3(1024, 1, Gc), 256, 0, stream>>>(bufA, bufB);
        k_softmax<<<dim3(16, 1, Gc), 256, 0, stream>>>(bufB, valid, bufA);
        k_gemm_W<<<dim3(8, 9, Gc), 256, 0, stream>>>(b_o, bufA, out, b0);
    }
}

// Round 2
// 800.667 us; speedup vs baseline: 2.2162x; 2.2162x over previous
//
#include <hip/hip_runtime.h>
#include <cmath>

#define CC 128
#define HH 64
#define WWI 64
#define LL 1024
#define NB 16
#define MM 1152          // 128 channels * 9 taps

// per-batch ws floats: b_dsT + f_dsT + n2/bnorm/valid + bufA + bufB + Abf(bf16)
#define PB_FLOATS (2*LL*CC + 3*LL + 2*LL*LL + (MM*LL/2))

#define BM 128
#define BN 128
#define BK 16

typedef __bf16 bf16x8 __attribute__((ext_vector_type(8)));
typedef float f32x4 __attribute__((ext_vector_type(4)));

#define GLDS(g, l) __builtin_amdgcn_global_load_lds( \
    (const __attribute__((address_space(1))) unsigned int*)(const void*)(g), \
    (__attribute__((address_space(3))) unsigned int*)(void*)(l), 16, 0, 0)

// ---- downsample + transpose to (batch, pixel, channel) ----
__global__ __launch_bounds__(256) void k_prep(const float* __restrict__ f_o,
                                              const float* __restrict__ b_o,
                                              float* __restrict__ f_dsT,
                                              float* __restrict__ b_dsT,
                                              int b0) {
    int t = blockIdx.x * 256 + threadIdx.x;
    int c  = t & 127;
    int u  = (t >> 7) & (LL - 1);
    int bz = t >> 17;
    int gb = b0 + bz;
    int uy = u >> 5, ux = u & 31;
    size_t src = ((size_t)(gb * CC + c) * HH + 2 * uy) * WWI + 2 * ux;
    size_t dst = ((size_t)bz * LL + u) * CC + c;
    f_dsT[dst] = f_o[src];
    b_dsT[dst] = b_o[src];
}

__global__ __launch_bounds__(256) void k_n2(const float* __restrict__ b_dsT,
                                            float* __restrict__ n2) {
    int t = blockIdx.x * 256 + threadIdx.x;
    const float4* row = (const float4*)(b_dsT + (size_t)t * CC);
    float s = 0.f;
#pragma unroll
    for (int i = 0; i < 32; i++) {
        float4 v = row[i];
        s += v.x * v.x + v.y * v.y + v.z * v.z + v.w * v.w;
    }
    n2[t] = s;
}

__global__ __launch_bounds__(256) void k_bnorm_valid(const float* __restrict__ n2,
                                                     const float* __restrict__ mask,
                                                     float* __restrict__ bnorm,
                                                     float* __restrict__ valid,
                                                     int b0) {
    int t = blockIdx.x * 256 + threadIdx.x;
    int p  = t & (LL - 1);
    int bz = t >> 10;
    int gb = b0 + bz;
    int py = p >> 5, px = p & 31;
    const float* mb = mask + (size_t)gb * HH * WWI;
    float s = 0.f, msum = 0.f;
#pragma unroll
    for (int dy = -1; dy <= 1; dy++) {
#pragma unroll
        for (int dx = -1; dx <= 1; dx++) {
            int py2 = py + dy, px2 = px + dx;
            if ((unsigned)py2 < 32u && (unsigned)px2 < 32u) {
                s    += n2[bz * LL + ((py2 << 5) | px2)];
                msum += mb[(2 * py2) * WWI + 2 * px2];
            }
        }
    }
    bnorm[t] = fmaxf(sqrtf(s), 1e-4f);
    valid[t] = (msum == 0.0f) ? 1.0f : 0.0f;
}

// ---- materialize A_bf16[m=(c,jy,jx)][p] = b_o[c, 2py+jy-1, 2px+jx-1] ----
__global__ __launch_bounds__(256) void k_makeA(const float* __restrict__ b_o,
                                               __bf16* __restrict__ Abf,
                                               int b0) {
    int bz = blockIdx.z, gb = b0 + bz;
    int e = blockIdx.x * 256 + threadIdx.x;   // 1152*1024 per batch
    int m = e >> 10, p = e & 1023;
    int c = m / 9, rem = m - 9 * c, jy = rem / 3, jx = rem - 3 * jy;
    int row = 2 * (p >> 5) + jy - 1;
    int col = 2 * (p & 31) + jx - 1;
    float v = 0.f;
    if ((unsigned)row < 64u && (unsigned)col < 64u)
        v = b_o[((size_t)(gb * CC + c) * HH + row) * WWI + col];
    Abf[((size_t)bz * MM + m) * LL + p] = (__bf16)v;
}

// ---- T[u,v] = sum_c b_ds[u,c]*f_ds[v,c]  (fp32, K=128) ----
__global__ __launch_bounds__(256) void k_gemm_T(const float* __restrict__ A,
                                                const float* __restrict__ B,
                                                float* __restrict__ Tout) {
    int bz = blockIdx.z;
    const float* Ab = A + (size_t)bz * LL * CC;
    const float* Bb = B + (size_t)bz * LL * CC;
    float* Tb = Tout + (size_t)bz * LL * LL;
    int m0 = blockIdx.y * BM, n0 = blockIdx.x * BN;
    __shared__ __align__(16) float As[BK][BM + 4];
    __shared__ __align__(16) float Bs[BK][BN + 4];
    int t = threadIdx.x;
    int kl = t & 15, rl = t >> 4;
    int tx = t & 15, ty = t >> 4;
    float acc[8][8] = {};
    for (int k0 = 0; k0 < CC; k0 += BK) {
#pragma unroll
        for (int i = 0; i < 8; i++) {
            int rr = rl + 16 * i;
            As[kl][rr] = Ab[(size_t)(m0 + rr) * CC + k0 + kl];
            Bs[kl][rr] = Bb[(size_t)(n0 + rr) * CC + k0 + kl];
        }
        __syncthreads();
#pragma unroll
        for (int k = 0; k < BK; k++) {
            float4 a0 = *(const float4*)&As[k][ty * 8];
            float4 a1 = *(const float4*)&As[k][ty * 8 + 4];
            float4 b0 = *(const float4*)&Bs[k][tx * 8];
            float4 b1 = *(const float4*)&Bs[k][tx * 8 + 4];
            float a[8] = {a0.x, a0.y, a0.z, a0.w, a1.x, a1.y, a1.z, a1.w};
            float b[8] = {b0.x, b0.y, b0.z, b0.w, b1.x, b1.y, b1.z, b1.w};
#pragma unroll
            for (int i = 0; i < 8; i++)
#pragma unroll
                for (int j = 0; j < 8; j++)
                    acc[i][j] = fmaf(a[i], b[j], acc[i][j]);
        }
        __syncthreads();
    }
#pragma unroll
    for (int i = 0; i < 8; i++) {
        float* dst = Tb + (size_t)(m0 + ty * 8 + i) * LL + n0 + tx * 8;
        float4 v0 = {acc[i][0], acc[i][1], acc[i][2], acc[i][3]};
        float4 v1 = {acc[i][4], acc[i][5], acc[i][6], acc[i][7]};
        *(float4*)dst = v0;
        *(float4*)(dst + 4) = v1;
    }
}

__global__ __launch_bounds__(256) void k_st1(const float* __restrict__ Tm,
                                             const float* __restrict__ bnorm,
                                             float* __restrict__ outp) {
    int bz = blockIdx.z;
    int p  = blockIdx.x;
    const float* Tb = Tm + (size_t)bz * LL * LL;
    float inv = 1.0f / bnorm[bz * LL + p];
    float* ob = outp + (size_t)bz * LL * LL + (size_t)p * LL;
    int py = p >> 5, px = p & 31;
    for (int q = threadIdx.x; q < LL; q += 256) {
        int qy = q >> 5, qx = q & 31;
        float acc = 0.f;
#pragma unroll
        for (int dy = -1; dy <= 1; dy++) {
#pragma unroll
            for (int dx = -1; dx <= 1; dx++) {
                int py2 = py + dy, px2 = px + dx, qy2 = qy + dy, qx2 = qx + dx;
                if ((unsigned)py2 < 32u && (unsigned)px2 < 32u &&
                    (unsigned)qy2 < 32u && (unsigned)qx2 < 32u)
                    acc += Tb[(size_t)((py2 << 5) | px2) * LL + ((qy2 << 5) | qx2)];
            }
        }
        ob[q] = acc * inv;
    }
}

__global__ __launch_bounds__(256) void k_st2(const float* __restrict__ in,
                                             float* __restrict__ outp) {
    int bz = blockIdx.z;
    int i  = blockIdx.x;
    const float* ib = in + (size_t)bz * LL * LL;
    float* ob = outp + (size_t)bz * LL * LL + (size_t)i * LL;
    for (int j = threadIdx.x; j < LL; j += 256) {
        float acc = 0.f;
#pragma unroll
        for (int k = -1; k <= 1; k++) {
            int ii = i + k, jj = j + k;
            if ((unsigned)ii < 1024u && (unsigned)jj < 1024u)
                acc += ib[(size_t)ii * LL + jj];
        }
        ob[j] = acc;
    }
}

__global__ __launch_bounds__(256) void k_st3(const float* __restrict__ in,
                                             float* __restrict__ outp) {
    int bz = blockIdx.z;
    int p  = blockIdx.x;
    const float* ib = in + (size_t)bz * LL * LL;
    float* ob = outp + (size_t)bz * LL * LL + (size_t)p * LL;
    int sp = ((p & 31) << 5) | (p >> 5);
    int rowv[3], rows[3];
#pragma unroll
    for (int k = 0; k < 3; k++) {
        int tp = sp + k - 1;
        rowv[k] = ((unsigned)tp < 1024u) ? 1 : 0;
        rows[k] = ((tp & 31) << 5) | ((tp >> 5) & 31);
    }
    for (int j = threadIdx.x; j < LL; j += 256) {
        int sq = ((j & 31) << 5) | (j >> 5);
        float acc = 0.f;
#pragma unroll
        for (int k = 0; k < 3; k++) {
            int tq = sq + k - 1;
            if (rowv[k] && (unsigned)tq < 1024u) {
                int col = ((tq & 31) << 5) | (tq >> 5);
                acc += ib[(size_t)rows[k] * LL + col];
            }
        }
        ob[j] = acc;
    }
}

__global__ __launch_bounds__(256) void k_softmax(const float* __restrict__ S,
                                                 const float* __restrict__ valid,
                                                 float* __restrict__ outS) {
    int bz = blockIdx.z;
    const float* Sb = S + (size_t)bz * LL * LL;
    const float* vb = valid + bz * LL;
    float* ob = outS + (size_t)bz * LL * LL;
    int lq = threadIdx.x & 63;
    int st = threadIdx.x >> 6;
    int q  = blockIdx.x * 64 + lq;
    __shared__ float red[4][64];
    float m = -1e30f;
    for (int p = st; p < LL; p += 4)
        m = fmaxf(m, Sb[(size_t)p * LL + q] * vb[p]);
    red[st][lq] = m;
    __syncthreads();
    m = fmaxf(fmaxf(red[0][lq], red[1][lq]), fmaxf(red[2][lq], red[3][lq]));
    __syncthreads();
    float s = 0.f;
    for (int p = st; p < LL; p += 4)
        s += __expf(10.f * (Sb[(size_t)p * LL + q] * vb[p] - m));
    red[st][lq] = s;
    __syncthreads();
    s = red[0][lq] + red[1][lq] + red[2][lq] + red[3][lq];
    float inv = 1.0f / s;
    for (int p = st; p < LL; p += 4) {
        float vl = vb[p];
        ob[(size_t)p * LL + q] = __expf(10.f * (Sb[(size_t)p * LL + q] * vl - m)) * inv * vl;
    }
}

// ---- transpose + bf16 cast: score[p][q] fp32 -> scoreT[q][p] bf16 ----
__global__ __launch_bounds__(256) void k_transp(const float* __restrict__ S,
                                                __bf16* __restrict__ St) {
    int bz = blockIdx.z;
    const float* Sb = S + (size_t)bz * LL * LL;
    __bf16* Tb = St + (size_t)bz * LL * LL;
    int q0 = blockIdx.x * 64, p0 = blockIdx.y * 64;
    __shared__ float tile[64][65];
    int t = threadIdx.x;
#pragma unroll
    for (int r = 0; r < 16; r++) {
        int idx = t + r * 256;
        int pl = idx >> 6, ql = idx & 63;
        tile[pl][ql] = Sb[(size_t)(p0 + pl) * LL + q0 + ql];
    }
    __syncthreads();
#pragma unroll
    for (int r = 0; r < 16; r++) {
        int idx = t + r * 256;
        int ql = idx >> 6, pl = idx & 63;
        Tb[(size_t)(q0 + ql) * LL + p0 + pl] = (__bf16)tile[pl][ql];
    }
}

// ---- MFMA GEMM: W[m,q] = sum_p Abf[m][p] * scoreT[q][p]; fused scatter ----
__global__ __launch_bounds__(256) void k_gemm_W_mfma(const __bf16* __restrict__ Abf,
                                                     const __bf16* __restrict__ St,
                                                     float* __restrict__ outp,
                                                     int b0) {
    int bz = blockIdx.z, gb = b0 + bz;
    const __bf16* Ab = Abf + (size_t)bz * MM * LL;
    const __bf16* Bb = St + (size_t)bz * LL * LL;
    int m0 = blockIdx.y * 128, n0 = blockIdx.x * 128;

    __shared__ __align__(16) __bf16 As[128 * 32];
    __shared__ __align__(16) __bf16 Bs[128 * 32];

    int t = threadIdx.x;
    int lane = t & 63, w = t >> 6;
    // staging mapping: lane -> (row-sub, k-group slot) with XOR swizzle
    int msub = lane >> 2;
    int kg   = (lane & 3) ^ ((lane >> 3) & 3);   // data k-group stored at slot lane&3
    // fragment-read constants
    int lm = lane & 15, kgf = lane >> 4;
    int sw = kgf ^ ((lm >> 1) & 3);
    int wm = (w & 1) * 64, wn = (w >> 1) * 64;

    const __bf16* gA[2]; const __bf16* gB[2];
    __bf16* lA[2]; __bf16* lB[2];
#pragma unroll
    for (int j = 0; j < 2; j++) {
        int rsub = w * 32 + j * 16 + msub;
        gA[j] = Ab + (size_t)(m0 + rsub) * LL + kg * 8;
        gB[j] = Bb + (size_t)(n0 + rsub) * LL + kg * 8;
        lA[j] = &As[(w * 32 + j * 16) * 32];
        lB[j] = &Bs[(w * 32 + j * 16) * 32];
    }

    f32x4 acc[4][4];
#pragma unroll
    for (int i = 0; i < 4; i++)
#pragma unroll
        for (int j = 0; j < 4; j++)
            acc[i][j] = (f32x4)0.0f;

    for (int k0 = 0; k0 < LL; k0 += 32) {
        __syncthreads();
#pragma unroll
        for (int j = 0; j < 2; j++) {
            GLDS(gA[j] + k0, lA[j]);
            GLDS(gB[j] + k0, lB[j]);
        }
        __syncthreads();
        bf16x8 af[4], bfr[4];
#pragma unroll
        for (int i = 0; i < 4; i++)
            af[i] = *(const bf16x8*)&As[(wm + i * 16 + lm) * 32 + sw * 8];
#pragma unroll
        for (int j = 0; j < 4; j++)
            bfr[j] = *(const bf16x8*)&Bs[(wn + j * 16 + lm) * 32 + sw * 8];
#pragma unroll
        for (int i = 0; i < 4; i++)
#pragma unroll
            for (int j = 0; j < 4; j++)
                acc[i][j] = __builtin_amdgcn_mfma_f32_16x16x32_bf16(af[i], bfr[j], acc[i][j], 0, 0, 0);
    }

    // scatter epilogue: W[m,q] -> out[c, 2qy+jy-1, 2qx+jx-1], each elem one target
    float* outb = outp + (size_t)gb * CC * HH * WWI;
#pragma unroll
    for (int i = 0; i < 4; i++) {
#pragma unroll
        for (int r = 0; r < 4; r++) {
            int m = m0 + wm + i * 16 + kgf * 4 + r;
            int c = m / 9, rem = m - 9 * c, jy = rem / 3, jx = rem - 3 * jy;
            float* ob = outb + (size_t)c * HH * WWI;
#pragma unroll
            for (int j = 0; j < 4; j++) {
                int n = n0 + wn + j * 16 + lm;
                int oy = 2 * (n >> 5) + jy - 1;
                int ox = 2 * (n & 31) + jx - 1;
                if ((unsigned)oy < 64u && (unsigned)ox < 64u)
                    atomicAdd(ob + oy * WWI + ox, 0.25f * acc[i][j][r]);
            }
        }
    }
}

extern "C" void kernel_launch(void* const* d_in, const int* in_sizes, int n_in,
                              void* d_out, int out_size, void* d_ws, size_t ws_size,
                              hipStream_t stream) {
    (void)in_sizes; (void)n_in;
    const float* f_o  = (const float*)d_in[0];
    const float* b_o  = (const float*)d_in[1];
    const float* mask = (const float*)d_in[2];
    float* out = (float*)d_out;

    hipMemsetAsync(d_out, 0, (size_t)out_size * sizeof(float), stream);

    size_t pb_bytes = (size_t)PB_FLOATS * sizeof(float);   // ~11.8 MB per batch
    int G = (int)(ws_size / pb_bytes);
    if (G < 1) G = 1;
    if (G > NB) G = NB;

    float* ws    = (float*)d_ws;
    float* b_dsT = ws;
    float* f_dsT = b_dsT + (size_t)G * LL * CC;
    float* n2    = f_dsT + (size_t)G * LL * CC;
    float* bnorm = n2 + (size_t)G * LL;
    float* valid = bnorm + (size_t)G * LL;
    float* bufA  = valid + (size_t)G * LL;
    float* bufB  = bufA + (size_t)G * LL * LL;
    __bf16* Abf  = (__bf16*)(bufB + (size_t)G * LL * LL);
    __bf16* scoreT = (__bf16*)bufB;   // reuses bufB after softmax

    for (int b0 = 0; b0 < NB; b0 += G) {
        int Gc = NB - b0 < G ? NB - b0 : G;
        k_prep<<<dim3(Gc * 512), 256, 0, stream>>>(f_o, b_o, f_dsT, b_dsT, b0);
        k_n2<<<dim3(Gc * 4), 256, 0, stream>>>(b_dsT, n2);
        k_bnorm_valid<<<dim3(Gc * 4), 256, 0, stream>>>(n2, mask, bnorm, valid, b0);
        k_makeA<<<dim3(4608, 1, Gc), 256, 0, stream>>>(b_o, Abf, b0);
        k_gemm_T<<<dim3(8, 8, Gc), 256, 0, stream>>>(b_dsT, f_dsT, bufA);
        k_st1<<<dim3(1024, 1, Gc), 256, 0, stream>>>(bufA, bnorm, bufB);
        k_st2<<<dim3(1024, 1, Gc), 256, 0, stream>>>(bufB, bufA);
        k_st3<<<dim3(1024, 1, Gc), 256, 0, stream>>>(bufA, bufB);
        k_softmax<<<dim3(16, 1, Gc), 256, 0, stream>>>(bufB, valid, bufA);
        k_transp<<<dim3(16, 16, Gc), 256, 0, stream>>>(bufA, scoreT);
        k_gemm_W_mfma<<<dim3(8, 9, Gc), 256, 0, stream>>>(Abf, scoreT, out, b0);
    }
}

// Round 3
// 575.096 us; speedup vs baseline: 3.0854x; 1.3922x over previous
//
#include <hip/hip_runtime.h>
#include <cmath>

#define CC 128
#define HH 64
#define WWI 64
#define LL 1024
#define NB 16
#define MM 1152          // 128 channels * 9 taps
#define KC 384           // concat K for bf16x3 T-GEMM

// per-batch ws: pool1 (max(bcat+fcat, Abf) = 1179648 bf16 = 589824 fl)
//             + n2/bnorm/valid (3*1024) + bufA + bufB (2*1024*1024)
#define PB_FLOATS (589824 + 3*LL + 2*LL*LL)

typedef __bf16 bf16x8 __attribute__((ext_vector_type(8)));
typedef __bf16 bf16x4 __attribute__((ext_vector_type(4)));
typedef float f32x4 __attribute__((ext_vector_type(4)));

#define GLDS(g, l) __builtin_amdgcn_global_load_lds( \
    (const __attribute__((address_space(1))) unsigned int*)(const void*)(g), \
    (__attribute__((address_space(3))) unsigned int*)(void*)(l), 16, 0, 0)

// ---- downsample + transpose + bf16 hi/lo split into concat K=384 layout ----
// bcat[u][0:128]=bhi [128:256]=bhi [256:384]=blo
// fcat[u][0:128]=fhi [128:256]=flo [256:384]=fhi
__global__ __launch_bounds__(256) void k_prep(const float* __restrict__ f_o,
                                              const float* __restrict__ b_o,
                                              __bf16* __restrict__ pool1,
                                              int b0) {
    int t = blockIdx.x * 256 + threadIdx.x;
    int c  = t & 127;
    int u  = (t >> 7) & (LL - 1);
    int bz = t >> 17;
    int gb = b0 + bz;
    int uy = u >> 5, ux = u & 31;
    size_t src = ((size_t)(gb * CC + c) * HH + 2 * uy) * WWI + 2 * ux;
    float fv = f_o[src];
    float bv = b_o[src];
    __bf16 fhi = (__bf16)fv; __bf16 flo = (__bf16)(fv - (float)fhi);
    __bf16 bhi = (__bf16)bv; __bf16 blo = (__bf16)(bv - (float)bhi);
    __bf16* bcat = pool1 + (size_t)bz * 1179648 + (size_t)u * KC;
    __bf16* fcat = bcat + 393216;
    bcat[c] = bhi; bcat[128 + c] = bhi; bcat[256 + c] = blo;
    fcat[c] = fhi; fcat[128 + c] = flo; fcat[256 + c] = fhi;
}

// ---- per-pixel sum of squares of downsampled b (from hi+lo) ----
__global__ __launch_bounds__(256) void k_n2(const __bf16* __restrict__ pool1,
                                            float* __restrict__ n2) {
    int t = blockIdx.x * 256 + threadIdx.x;   // bz*LL + u
    int bz = t >> 10, u = t & (LL - 1);
    const __bf16* row = pool1 + (size_t)bz * 1179648 + (size_t)u * KC;
    const bf16x8* hi = (const bf16x8*)row;
    const bf16x8* lo = (const bf16x8*)(row + 256);
    float s = 0.f;
#pragma unroll
    for (int i = 0; i < 16; i++) {
        bf16x8 h = hi[i], l = lo[i];
#pragma unroll
        for (int e = 0; e < 8; e++) {
            float b = (float)h[e] + (float)l[e];
            s += b * b;
        }
    }
    n2[t] = s;
}

__global__ __launch_bounds__(256) void k_bnorm_valid(const float* __restrict__ n2,
                                                     const float* __restrict__ mask,
                                                     float* __restrict__ bnorm,
                                                     float* __restrict__ valid,
                                                     int b0) {
    int t = blockIdx.x * 256 + threadIdx.x;
    int p  = t & (LL - 1);
    int bz = t >> 10;
    int gb = b0 + bz;
    int py = p >> 5, px = p & 31;
    const float* mb = mask + (size_t)gb * HH * WWI;
    float s = 0.f, msum = 0.f;
#pragma unroll
    for (int dy = -1; dy <= 1; dy++) {
#pragma unroll
        for (int dx = -1; dx <= 1; dx++) {
            int py2 = py + dy, px2 = px + dx;
            if ((unsigned)py2 < 32u && (unsigned)px2 < 32u) {
                s    += n2[bz * LL + ((py2 << 5) | px2)];
                msum += mb[(2 * py2) * WWI + 2 * px2];
            }
        }
    }
    bnorm[t] = fmaxf(sqrtf(s), 1e-4f);
    valid[t] = (msum == 0.0f) ? 1.0f : 0.0f;
}

// ---- MFMA GEMM: T[u,v] = sum_k bcat[u,k]*fcat[v,k], K=384 (bf16x3 == fp32) ----
__global__ __launch_bounds__(256) void k_gemm_T_mfma(const __bf16* __restrict__ pool1,
                                                     float* __restrict__ Tout) {
    int bz = blockIdx.z;
    const __bf16* Ab = pool1 + (size_t)bz * 1179648;            // bcat
    const __bf16* Bb = Ab + 393216;                              // fcat
    float* Tb = Tout + (size_t)bz * LL * LL;
    int m0 = blockIdx.y * 128, n0 = blockIdx.x * 128;

    __shared__ __align__(16) __bf16 As[128 * 32];
    __shared__ __align__(16) __bf16 Bs[128 * 32];

    int t = threadIdx.x;
    int lane = t & 63, w = t >> 6;
    int msub = lane >> 2;
    int kg   = (lane & 3) ^ ((lane >> 3) & 3);
    int lm = lane & 15, kgf = lane >> 4;
    int sw = kgf ^ ((lm >> 1) & 3);
    int wm = (w & 1) * 64, wn = (w >> 1) * 64;

    const __bf16* gA[2]; const __bf16* gB[2];
    __bf16* lA[2]; __bf16* lB[2];
#pragma unroll
    for (int j = 0; j < 2; j++) {
        int rsub = w * 32 + j * 16 + msub;
        gA[j] = Ab + (size_t)(m0 + rsub) * KC + kg * 8;
        gB[j] = Bb + (size_t)(n0 + rsub) * KC + kg * 8;
        lA[j] = &As[(w * 32 + j * 16) * 32];
        lB[j] = &Bs[(w * 32 + j * 16) * 32];
    }

    f32x4 acc[4][4];
#pragma unroll
    for (int i = 0; i < 4; i++)
#pragma unroll
        for (int j = 0; j < 4; j++)
            acc[i][j] = (f32x4)0.0f;

    for (int k0 = 0; k0 < KC; k0 += 32) {
        __syncthreads();
#pragma unroll
        for (int j = 0; j < 2; j++) {
            GLDS(gA[j] + k0, lA[j]);
            GLDS(gB[j] + k0, lB[j]);
        }
        __syncthreads();
        bf16x8 af[4], bfr[4];
#pragma unroll
        for (int i = 0; i < 4; i++)
            af[i] = *(const bf16x8*)&As[(wm + i * 16 + lm) * 32 + sw * 8];
#pragma unroll
        for (int j = 0; j < 4; j++)
            bfr[j] = *(const bf16x8*)&Bs[(wn + j * 16 + lm) * 32 + sw * 8];
#pragma unroll
        for (int i = 0; i < 4; i++)
#pragma unroll
            for (int j = 0; j < 4; j++)
                acc[i][j] = __builtin_amdgcn_mfma_f32_16x16x32_bf16(af[i], bfr[j], acc[i][j], 0, 0, 0);
    }

#pragma unroll
    for (int i = 0; i < 4; i++) {
#pragma unroll
        for (int r = 0; r < 4; r++) {
            int m = m0 + wm + i * 16 + kgf * 4 + r;
            float* dst = Tb + (size_t)m * LL + n0 + wn + lm;
#pragma unroll
            for (int j = 0; j < 4; j++)
                dst[j * 16] = acc[i][j][r];
        }
    }
}

// ---- S1[p,q] = (sum_{dy,dx} T[p+d, q+d]) / bnorm[p]  (2D bounds) ----
__global__ __launch_bounds__(256) void k_st1(const float* __restrict__ Tm,
                                             const float* __restrict__ bnorm,
                                             float* __restrict__ outp) {
    int bz = blockIdx.z;
    int p  = blockIdx.x;
    const float* Tb = Tm + (size_t)bz * LL * LL;
    float inv = 1.0f / bnorm[bz * LL + p];
    float* ob = outp + (size_t)bz * LL * LL + (size_t)p * LL;
    int py = p >> 5, px = p & 31;
    for (int q = threadIdx.x; q < LL; q += 256) {
        int qy = q >> 5, qx = q & 31;
        float acc = 0.f;
#pragma unroll
        for (int dy = -1; dy <= 1; dy++) {
#pragma unroll
            for (int dx = -1; dx <= 1; dx++) {
                int py2 = py + dy, px2 = px + dx, qy2 = qy + dy, qx2 = qx + dx;
                if ((unsigned)py2 < 32u && (unsigned)px2 < 32u &&
                    (unsigned)qy2 < 32u && (unsigned)qx2 < 32u)
                    acc += Tb[(size_t)((py2 << 5) | px2) * LL + ((qy2 << 5) | qx2)];
            }
        }
        ob[q] = acc * inv;
    }
}

// ---- first diag_fuse, flat-index space ----
__global__ __launch_bounds__(256) void k_st2(const float* __restrict__ in,
                                             float* __restrict__ outp) {
    int bz = blockIdx.z;
    int i  = blockIdx.x;
    const float* ib = in + (size_t)bz * LL * LL;
    float* ob = outp + (size_t)bz * LL * LL + (size_t)i * LL;
    for (int j = threadIdx.x; j < LL; j += 256) {
        float acc = 0.f;
#pragma unroll
        for (int k = -1; k <= 1; k++) {
            int ii = i + k, jj = j + k;
            if ((unsigned)ii < 1024u && (unsigned)jj < 1024u)
                acc += ib[(size_t)ii * LL + jj];
        }
        ob[j] = acc;
    }
}

// ---- second diag_fuse (sigma-space) fused with transpose: out ST[q][p] ----
__global__ __launch_bounds__(256) void k_st3t(const float* __restrict__ in,
                                              float* __restrict__ outp) {
    int bz = blockIdx.z;
    const float* ib = in + (size_t)bz * LL * LL;
    float* ob = outp + (size_t)bz * LL * LL;
    int p0 = blockIdx.y * 64, q0 = blockIdx.x * 64;
    __shared__ float tile[64][65];
    int t = threadIdx.x;
#pragma unroll
    for (int it = 0; it < 16; it++) {
        int e = it * 256 + t;
        int pl = e >> 6, ql = e & 63;
        int p = p0 + pl, q = q0 + ql;
        int sp = ((p & 31) << 5) | (p >> 5);
        int sq = ((q & 31) << 5) | (q >> 5);
        float acc = 0.f;
#pragma unroll
        for (int k = -1; k <= 1; k++) {
            int tp = sp + k, tq = sq + k;
            if ((unsigned)tp < 1024u && (unsigned)tq < 1024u) {
                int row = ((tp & 31) << 5) | (tp >> 5);
                int col = ((tq & 31) << 5) | (tq >> 5);
                acc += ib[(size_t)row * LL + col];
            }
        }
        tile[pl][ql] = acc;
    }
    __syncthreads();
#pragma unroll
    for (int it = 0; it < 16; it++) {
        int e = it * 256 + t;
        int ql = e >> 6, pl = e & 63;
        ob[(size_t)(q0 + ql) * LL + p0 + pl] = tile[pl][ql];
    }
}

// ---- row softmax on ST (contiguous over p), writes bf16 scoreT[q][p] ----
__global__ __launch_bounds__(256) void k_softmax_bf(const float* __restrict__ ST,
                                                    const float* __restrict__ valid,
                                                    __bf16* __restrict__ outS) {
    int bz = blockIdx.z;
    int lane = threadIdx.x & 63;
    int q = blockIdx.x * 4 + (threadIdx.x >> 6);
    const float* row = ST + ((size_t)bz * LL + q) * LL;
    const float* vb  = valid + bz * LL;
    __bf16* orow = outS + ((size_t)bz * LL + q) * LL;

    float4 v[4], vl[4];
#pragma unroll
    for (int i = 0; i < 4; i++) {
        int p = lane * 4 + i * 256;
        float4 s = *(const float4*)(row + p);
        float4 m = *(const float4*)(vb + p);
        v[i] = {s.x * m.x, s.y * m.y, s.z * m.z, s.w * m.w};
        vl[i] = m;
    }
    float mx = -1e30f;
#pragma unroll
    for (int i = 0; i < 4; i++)
        mx = fmaxf(mx, fmaxf(fmaxf(v[i].x, v[i].y), fmaxf(v[i].z, v[i].w)));
#pragma unroll
    for (int k = 1; k < 64; k <<= 1)
        mx = fmaxf(mx, __shfl_xor(mx, k, 64));
    float sum = 0.f;
    float4 e[4];
#pragma unroll
    for (int i = 0; i < 4; i++) {
        e[i].x = __expf(10.f * (v[i].x - mx));
        e[i].y = __expf(10.f * (v[i].y - mx));
        e[i].z = __expf(10.f * (v[i].z - mx));
        e[i].w = __expf(10.f * (v[i].w - mx));
        sum += e[i].x + e[i].y + e[i].z + e[i].w;
    }
#pragma unroll
    for (int k = 1; k < 64; k <<= 1)
        sum += __shfl_xor(sum, k, 64);
    float inv = 1.0f / sum;
#pragma unroll
    for (int i = 0; i < 4; i++) {
        bf16x4 o;
        o[0] = (__bf16)(e[i].x * inv * vl[i].x);
        o[1] = (__bf16)(e[i].y * inv * vl[i].y);
        o[2] = (__bf16)(e[i].z * inv * vl[i].z);
        o[3] = (__bf16)(e[i].w * inv * vl[i].w);
        *(bf16x4*)(orow + lane * 4 + i * 256) = o;
    }
}

// ---- materialize A_bf16[m=(c,jy,jx)][p] (overwrites dead bcat/fcat pool) ----
__global__ __launch_bounds__(256) void k_makeA(const float* __restrict__ b_o,
                                               __bf16* __restrict__ pool1,
                                               int b0) {
    int bz = blockIdx.z, gb = b0 + bz;
    int e = blockIdx.x * 256 + threadIdx.x;   // 1152*1024 per batch
    int m = e >> 10, p = e & 1023;
    int c = m / 9, rem = m - 9 * c, jy = rem / 3, jx = rem - 3 * jy;
    int row = 2 * (p >> 5) + jy - 1;
    int col = 2 * (p & 31) + jx - 1;
    float v = 0.f;
    if ((unsigned)row < 64u && (unsigned)col < 64u)
        v = b_o[((size_t)(gb * CC + c) * HH + row) * WWI + col];
    pool1[(size_t)bz * 1179648 + (size_t)m * LL + p] = (__bf16)v;
}

// ---- MFMA GEMM W[m,q] = sum_p Abf[m][p]*scoreT[q][p]; fused scatter ----
__global__ __launch_bounds__(256) void k_gemm_W_mfma(const __bf16* __restrict__ pool1,
                                                     const __bf16* __restrict__ St,
                                                     float* __restrict__ outp,
                                                     int b0) {
    int bz = blockIdx.z, gb = b0 + bz;
    const __bf16* Ab = pool1 + (size_t)bz * 1179648;
    const __bf16* Bb = St + (size_t)bz * LL * LL;
    int m0 = blockIdx.y * 128, n0 = blockIdx.x * 128;

    __shared__ __align__(16) __bf16 As[128 * 32];
    __shared__ __align__(16) __bf16 Bs[128 * 32];

    int t = threadIdx.x;
    int lane = t & 63, w = t >> 6;
    int msub = lane >> 2;
    int kg   = (lane & 3) ^ ((lane >> 3) & 3);
    int lm = lane & 15, kgf = lane >> 4;
    int sw = kgf ^ ((lm >> 1) & 3);
    int wm = (w & 1) * 64, wn = (w >> 1) * 64;

    const __bf16* gA[2]; const __bf16* gB[2];
    __bf16* lA[2]; __bf16* lB[2];
#pragma unroll
    for (int j = 0; j < 2; j++) {
        int rsub = w * 32 + j * 16 + msub;
        gA[j] = Ab + (size_t)(m0 + rsub) * LL + kg * 8;
        gB[j] = Bb + (size_t)(n0 + rsub) * LL + kg * 8;
        lA[j] = &As[(w * 32 + j * 16) * 32];
        lB[j] = &Bs[(w * 32 + j * 16) * 32];
    }

    f32x4 acc[4][4];
#pragma unroll
    for (int i = 0; i < 4; i++)
#pragma unroll
        for (int j = 0; j < 4; j++)
            acc[i][j] = (f32x4)0.0f;

    for (int k0 = 0; k0 < LL; k0 += 32) {
        __syncthreads();
#pragma unroll
        for (int j = 0; j < 2; j++) {
            GLDS(gA[j] + k0, lA[j]);
            GLDS(gB[j] + k0, lB[j]);
        }
        __syncthreads();
        bf16x8 af[4], bfr[4];
#pragma unroll
        for (int i = 0; i < 4; i++)
            af[i] = *(const bf16x8*)&As[(wm + i * 16 + lm) * 32 + sw * 8];
#pragma unroll
        for (int j = 0; j < 4; j++)
            bfr[j] = *(const bf16x8*)&Bs[(wn + j * 16 + lm) * 32 + sw * 8];
#pragma unroll
        for (int i = 0; i < 4; i++)
#pragma unroll
            for (int j = 0; j < 4; j++)
                acc[i][j] = __builtin_amdgcn_mfma_f32_16x16x32_bf16(af[i], bfr[j], acc[i][j], 0, 0, 0);
    }

    float* outb = outp + (size_t)gb * CC * HH * WWI;
#pragma unroll
    for (int i = 0; i < 4; i++) {
#pragma unroll
        for (int r = 0; r < 4; r++) {
            int m = m0 + wm + i * 16 + kgf * 4 + r;
            int c = m / 9, rem = m - 9 * c, jy = rem / 3, jx = rem - 3 * jy;
            float* ob = outb + (size_t)c * HH * WWI;
#pragma unroll
            for (int j = 0; j < 4; j++) {
                int n = n0 + wn + j * 16 + lm;
                int oy = 2 * (n >> 5) + jy - 1;
                int ox = 2 * (n & 31) + jx - 1;
                if ((unsigned)oy < 64u && (unsigned)ox < 64u)
                    atomicAdd(ob + oy * WWI + ox, 0.25f * acc[i][j][r]);
            }
        }
    }
}

extern "C" void kernel_launch(void* const* d_in, const int* in_sizes, int n_in,
                              void* d_out, int out_size, void* d_ws, size_t ws_size,
                              hipStream_t stream) {
    (void)in_sizes; (void)n_in;
    const float* f_o  = (const float*)d_in[0];
    const float* b_o  = (const float*)d_in[1];
    const float* mask = (const float*)d_in[2];
    float* out = (float*)d_out;

    hipMemsetAsync(d_out, 0, (size_t)out_size * sizeof(float), stream);

    size_t pb_bytes = (size_t)PB_FLOATS * sizeof(float);   // ~10.8 MB per batch
    int G = (int)(ws_size / pb_bytes);
    if (G < 1) G = 1;
    if (G > NB) G = NB;

    __bf16* pool1 = (__bf16*)d_ws;                       // G * 1179648 bf16
    float* fbase  = (float*)d_ws + (size_t)G * 589824;
    float* n2    = fbase;
    float* bnorm = n2 + (size_t)G * LL;
    float* valid = bnorm + (size_t)G * LL;
    float* bufA  = valid + (size_t)G * LL;
    float* bufB  = bufA + (size_t)G * LL * LL;
    __bf16* scoreT = (__bf16*)bufA;   // written by softmax after bufA(S2) is dead

    for (int b0 = 0; b0 < NB; b0 += G) {
        int Gc = NB - b0 < G ? NB - b0 : G;
        k_prep<<<dim3(Gc * 512), 256, 0, stream>>>(f_o, b_o, pool1, b0);
        k_n2<<<dim3(Gc * 4), 256, 0, stream>>>(pool1, n2);
        k_bnorm_valid<<<dim3(Gc * 4), 256, 0, stream>>>(n2, mask, bnorm, valid, b0);
        k_gemm_T_mfma<<<dim3(8, 8, Gc), 256, 0, stream>>>(pool1, bufA);
        k_st1<<<dim3(1024, 1, Gc), 256, 0, stream>>>(bufA, bnorm, bufB);
        k_st2<<<dim3(1024, 1, Gc), 256, 0, stream>>>(bufB, bufA);
        k_st3t<<<dim3(16, 16, Gc), 256, 0, stream>>>(bufA, bufB);
        k_softmax_bf<<<dim3(256, 1, Gc), 256, 0, stream>>>(bufB, valid, scoreT);
        k_makeA<<<dim3(4608, 1, Gc), 256, 0, stream>>>(b_o, pool1, b0);
        k_gemm_W_mfma<<<dim3(8, 9, Gc), 256, 0, stream>>>(pool1, scoreT, out, b0);
    }
}

// Round 4
// 496.439 us; speedup vs baseline: 3.5742x; 1.1584x over previous
//
#include <hip/hip_runtime.h>
#include <cmath>

#define CC 128
#define HH 64
#define WWI 64
#define LL 1024
#define NB 16
#define MM 1152          // 128 channels * 9 taps
#define KC 384           // concat K for bf16x3 T-GEMM

// per-batch slab layout (floats):
//  [0, 589824)           pool1: bcat+fcat (bf16 x 1179648), later Abf (bf16 x 1179648)
//  [589824, 590848)      n2
//  [590848, 591872)      bnorm
//  [591872, 592896)      valid
//  [592896, 1641472)     bufA (T, S2); first 524288 fl reused as scoreT (bf16 x 1M)
//  [1641472, 2690048)    bufB (S1, S3T)
//  W (fp32 x 1179648) overlays [1117184, 2296832) = bufA tail + bufB head,
//  written by gemm_W AFTER softmax consumed S3T; scoreT region not overlapped.
#define SLAB 2690048ul
#define OFF_N2    589824
#define OFF_BNORM 590848
#define OFF_VALID 591872
#define OFF_A     592896
#define OFF_B     1641472
#define OFF_W     1117184

typedef __bf16 bf16x8 __attribute__((ext_vector_type(8)));
typedef __bf16 bf16x4 __attribute__((ext_vector_type(4)));
typedef float f32x4 __attribute__((ext_vector_type(4)));

#define GLDS(g, l) __builtin_amdgcn_global_load_lds( \
    (const __attribute__((address_space(1))) unsigned int*)(const void*)(g), \
    (__attribute__((address_space(3))) unsigned int*)(void*)(l), 16, 0, 0)

// ---- downsample + transpose + bf16 hi/lo split into concat K=384 layout ----
__global__ __launch_bounds__(256) void k_prep(const float* __restrict__ f_o,
                                              const float* __restrict__ b_o,
                                              float* __restrict__ ws,
                                              int b0) {
    int t = blockIdx.x * 256 + threadIdx.x;
    int c  = t & 127;
    int u  = (t >> 7) & (LL - 1);
    int bz = t >> 17;
    int gb = b0 + bz;
    int uy = u >> 5, ux = u & 31;
    size_t src = ((size_t)(gb * CC + c) * HH + 2 * uy) * WWI + 2 * ux;
    float fv = f_o[src];
    float bv = b_o[src];
    __bf16 fhi = (__bf16)fv; __bf16 flo = (__bf16)(fv - (float)fhi);
    __bf16 bhi = (__bf16)bv; __bf16 blo = (__bf16)(bv - (float)bhi);
    __bf16* bcat = (__bf16*)(ws + (size_t)bz * SLAB) + (size_t)u * KC;
    __bf16* fcat = bcat + 393216;
    bcat[c] = bhi; bcat[128 + c] = bhi; bcat[256 + c] = blo;
    fcat[c] = fhi; fcat[128 + c] = flo; fcat[256 + c] = fhi;
}

// ---- per-pixel sum of squares of downsampled b (from hi+lo) ----
__global__ __launch_bounds__(256) void k_n2(float* __restrict__ ws) {
    int t = blockIdx.x * 256 + threadIdx.x;   // bz*LL + u
    int bz = t >> 10, u = t & (LL - 1);
    const __bf16* row = (const __bf16*)(ws + (size_t)bz * SLAB) + (size_t)u * KC;
    const bf16x8* hi = (const bf16x8*)row;
    const bf16x8* lo = (const bf16x8*)(row + 256);
    float s = 0.f;
#pragma unroll
    for (int i = 0; i < 16; i++) {
        bf16x8 h = hi[i], l = lo[i];
#pragma unroll
        for (int e = 0; e < 8; e++) {
            float b = (float)h[e] + (float)l[e];
            s += b * b;
        }
    }
    ws[(size_t)bz * SLAB + OFF_N2 + u] = s;
}

__global__ __launch_bounds__(256) void k_bnorm_valid(float* __restrict__ ws,
                                                     const float* __restrict__ mask,
                                                     int b0) {
    int t = blockIdx.x * 256 + threadIdx.x;
    int p  = t & (LL - 1);
    int bz = t >> 10;
    int gb = b0 + bz;
    int py = p >> 5, px = p & 31;
    const float* mb = mask + (size_t)gb * HH * WWI;
    const float* n2 = ws + (size_t)bz * SLAB + OFF_N2;
    float s = 0.f, msum = 0.f;
#pragma unroll
    for (int dy = -1; dy <= 1; dy++) {
#pragma unroll
        for (int dx = -1; dx <= 1; dx++) {
            int py2 = py + dy, px2 = px + dx;
            if ((unsigned)py2 < 32u && (unsigned)px2 < 32u) {
                s    += n2[(py2 << 5) | px2];
                msum += mb[(2 * py2) * WWI + 2 * px2];
            }
        }
    }
    ws[(size_t)bz * SLAB + OFF_BNORM + p] = fmaxf(sqrtf(s), 1e-4f);
    ws[(size_t)bz * SLAB + OFF_VALID + p] = (msum == 0.0f) ? 1.0f : 0.0f;
}

// ---- shared 128x128-tile BK=64 MFMA GEMM core (A,B both K-contiguous) ----
// LDS layout: row-major [128][64] bf16; granule = 8 bf16 (16B); granule g of
// row r stored at slot g^(r&7). Staging swizzle applied on the GLOBAL address
// (per-lane legal); GLDS dst stays wave-uniform base + lane*16B.
template<int KTOT>
__device__ __forceinline__ void gemm_core(const __bf16* __restrict__ Ab,
                                          const __bf16* __restrict__ Bb,
                                          int lda, int ldb, int m0, int n0,
                                          __bf16* As, __bf16* Bs,
                                          f32x4 acc[4][4]) {
    int t = threadIdx.x;
    int lane = t & 63, w = t >> 6;
    int rsub = lane >> 3;
    int g8   = ((lane & 7) ^ (rsub & 7)) * 8;
    int lm = lane & 15, kgf = lane >> 4;
    int wm = (w & 1) * 64, wn = (w >> 1) * 64;

    for (int k0 = 0; k0 < KTOT; k0 += 64) {
        __syncthreads();
#pragma unroll
        for (int ci = 0; ci < 4; ci++) {
            int rb = ci * 32 + w * 8;
            int r  = rb + rsub;
            GLDS(Ab + (size_t)(m0 + r) * lda + k0 + g8, &As[rb * 64]);
            GLDS(Bb + (size_t)(n0 + r) * ldb + k0 + g8, &Bs[rb * 64]);
        }
        __syncthreads();
#pragma unroll
        for (int s2 = 0; s2 < 2; s2++) {
            bf16x8 af[4], bfr[4];
#pragma unroll
            for (int i = 0; i < 4; i++)
                af[i] = *(const bf16x8*)&As[(wm + i * 16 + lm) * 64 + (((s2 * 4 + kgf) ^ (lm & 7)) * 8)];
#pragma unroll
            for (int j = 0; j < 4; j++)
                bfr[j] = *(const bf16x8*)&Bs[(wn + j * 16 + lm) * 64 + (((s2 * 4 + kgf) ^ (lm & 7)) * 8)];
#pragma unroll
            for (int i = 0; i < 4; i++)
#pragma unroll
                for (int j = 0; j < 4; j++)
                    acc[i][j] = __builtin_amdgcn_mfma_f32_16x16x32_bf16(af[i], bfr[j], acc[i][j], 0, 0, 0);
        }
    }
}

// ---- T[u,v] = sum_k bcat[u,k]*fcat[v,k], K=384 (bf16x3 == fp32) ----
__global__ __launch_bounds__(256) void k_gemm_T_mfma(float* __restrict__ ws) {
    int bz = blockIdx.z;
    const __bf16* Ab = (const __bf16*)(ws + (size_t)bz * SLAB);
    const __bf16* Bb = Ab + 393216;
    float* Tb = ws + (size_t)bz * SLAB + OFF_A;
    int m0 = blockIdx.y * 128, n0 = blockIdx.x * 128;
    __shared__ __align__(16) __bf16 As[128 * 64];
    __shared__ __align__(16) __bf16 Bs[128 * 64];
    f32x4 acc[4][4];
#pragma unroll
    for (int i = 0; i < 4; i++)
#pragma unroll
        for (int j = 0; j < 4; j++) acc[i][j] = (f32x4)0.0f;
    gemm_core<KC>(Ab, Bb, KC, KC, m0, n0, As, Bs, acc);
    int lane = threadIdx.x & 63, w = threadIdx.x >> 6;
    int lm = lane & 15, kgf = lane >> 4;
    int wm = (w & 1) * 64, wn = (w >> 1) * 64;
#pragma unroll
    for (int i = 0; i < 4; i++) {
#pragma unroll
        for (int r = 0; r < 4; r++) {
            int m = m0 + wm + i * 16 + kgf * 4 + r;
            float* dst = Tb + (size_t)m * LL + n0 + wn + lm;
#pragma unroll
            for (int j = 0; j < 4; j++)
                dst[j * 16] = acc[i][j][r];
        }
    }
}

// ---- S1[p,q] = (sum 3x3 diag T) / bnorm[p] ----
__global__ __launch_bounds__(256) void k_st1(float* __restrict__ ws) {
    int bz = blockIdx.z;
    int p  = blockIdx.x;
    const float* Tb = ws + (size_t)bz * SLAB + OFF_A;
    float inv = 1.0f / ws[(size_t)bz * SLAB + OFF_BNORM + p];
    float* ob = ws + (size_t)bz * SLAB + OFF_B + (size_t)p * LL;
    int py = p >> 5, px = p & 31;
    for (int q = threadIdx.x; q < LL; q += 256) {
        int qy = q >> 5, qx = q & 31;
        float acc = 0.f;
#pragma unroll
        for (int dy = -1; dy <= 1; dy++) {
#pragma unroll
            for (int dx = -1; dx <= 1; dx++) {
                int py2 = py + dy, px2 = px + dx, qy2 = qy + dy, qx2 = qx + dx;
                if ((unsigned)py2 < 32u && (unsigned)px2 < 32u &&
                    (unsigned)qy2 < 32u && (unsigned)qx2 < 32u)
                    acc += Tb[(size_t)((py2 << 5) | px2) * LL + ((qy2 << 5) | qx2)];
            }
        }
        ob[q] = acc * inv;
    }
}

// ---- first diag_fuse, flat-index space ----
__global__ __launch_bounds__(256) void k_st2(float* __restrict__ ws) {
    int bz = blockIdx.z;
    int i  = blockIdx.x;
    const float* ib = ws + (size_t)bz * SLAB + OFF_B;
    float* ob = ws + (size_t)bz * SLAB + OFF_A + (size_t)i * LL;
    for (int j = threadIdx.x; j < LL; j += 256) {
        float acc = 0.f;
#pragma unroll
        for (int k = -1; k <= 1; k++) {
            int ii = i + k, jj = j + k;
            if ((unsigned)ii < 1024u && (unsigned)jj < 1024u)
                acc += ib[(size_t)ii * LL + jj];
        }
        ob[j] = acc;
    }
}

// ---- second diag_fuse (sigma-space) fused with transpose: S3T[q][p] ----
__global__ __launch_bounds__(256) void k_st3t(float* __restrict__ ws) {
    int bz = blockIdx.z;
    const float* ib = ws + (size_t)bz * SLAB + OFF_A;
    float* ob = ws + (size_t)bz * SLAB + OFF_B;
    int p0 = blockIdx.y * 64, q0 = blockIdx.x * 64;
    __shared__ float tile[64][65];
    int t = threadIdx.x;
#pragma unroll
    for (int it = 0; it < 16; it++) {
        int e = it * 256 + t;
        int pl = e >> 6, ql = e & 63;
        int p = p0 + pl, q = q0 + ql;
        int sp = ((p & 31) << 5) | (p >> 5);
        int sq = ((q & 31) << 5) | (q >> 5);
        float acc = 0.f;
#pragma unroll
        for (int k = -1; k <= 1; k++) {
            int tp = sp + k, tq = sq + k;
            if ((unsigned)tp < 1024u && (unsigned)tq < 1024u) {
                int row = ((tp & 31) << 5) | (tp >> 5);
                int col = ((tq & 31) << 5) | (tq >> 5);
                acc += ib[(size_t)row * LL + col];
            }
        }
        tile[pl][ql] = acc;
    }
    __syncthreads();
#pragma unroll
    for (int it = 0; it < 16; it++) {
        int e = it * 256 + t;
        int ql = e >> 6, pl = e & 63;
        ob[(size_t)(q0 + ql) * LL + p0 + pl] = tile[pl][ql];
    }
}

// ---- row softmax on S3T (contiguous over p), writes bf16 scoreT[q][p] ----
__global__ __launch_bounds__(256) void k_softmax_bf(float* __restrict__ ws) {
    int bz = blockIdx.z;
    int lane = threadIdx.x & 63;
    int q = blockIdx.x * 4 + (threadIdx.x >> 6);
    const float* row = ws + (size_t)bz * SLAB + OFF_B + (size_t)q * LL;
    const float* vb  = ws + (size_t)bz * SLAB + OFF_VALID;
    __bf16* orow = (__bf16*)(ws + (size_t)bz * SLAB + OFF_A) + (size_t)q * LL;

    float4 v[4], vl[4];
#pragma unroll
    for (int i = 0; i < 4; i++) {
        int p = lane * 4 + i * 256;
        float4 s = *(const float4*)(row + p);
        float4 m = *(const float4*)(vb + p);
        v[i] = {s.x * m.x, s.y * m.y, s.z * m.z, s.w * m.w};
        vl[i] = m;
    }
    float mx = -1e30f;
#pragma unroll
    for (int i = 0; i < 4; i++)
        mx = fmaxf(mx, fmaxf(fmaxf(v[i].x, v[i].y), fmaxf(v[i].z, v[i].w)));
#pragma unroll
    for (int k = 1; k < 64; k <<= 1)
        mx = fmaxf(mx, __shfl_xor(mx, k, 64));
    float sum = 0.f;
    float4 e[4];
#pragma unroll
    for (int i = 0; i < 4; i++) {
        e[i].x = __expf(10.f * (v[i].x - mx));
        e[i].y = __expf(10.f * (v[i].y - mx));
        e[i].z = __expf(10.f * (v[i].z - mx));
        e[i].w = __expf(10.f * (v[i].w - mx));
        sum += e[i].x + e[i].y + e[i].z + e[i].w;
    }
#pragma unroll
    for (int k = 1; k < 64; k <<= 1)
        sum += __shfl_xor(sum, k, 64);
    float inv = 1.0f / sum;
#pragma unroll
    for (int i = 0; i < 4; i++) {
        bf16x4 o;
        o[0] = (__bf16)(e[i].x * inv * vl[i].x);
        o[1] = (__bf16)(e[i].y * inv * vl[i].y);
        o[2] = (__bf16)(e[i].z * inv * vl[i].z);
        o[3] = (__bf16)(e[i].w * inv * vl[i].w);
        *(bf16x4*)(orow + lane * 4 + i * 256) = o;
    }
}

// ---- materialize A_bf16[m=(c,jy,jx)][p] over dead bcat/fcat ----
__global__ __launch_bounds__(256) void k_makeA(const float* __restrict__ b_o,
                                               float* __restrict__ ws,
                                               int b0) {
    int bz = blockIdx.z, gb = b0 + bz;
    int e = blockIdx.x * 256 + threadIdx.x;
    int m = e >> 10, p = e & 1023;
    int c = m / 9, rem = m - 9 * c, jy = rem / 3, jx = rem - 3 * jy;
    int row = 2 * (p >> 5) + jy - 1;
    int col = 2 * (p & 31) + jx - 1;
    float v = 0.f;
    if ((unsigned)row < 64u && (unsigned)col < 64u)
        v = b_o[((size_t)(gb * CC + c) * HH + row) * WWI + col];
    ((__bf16*)(ws + (size_t)bz * SLAB))[(size_t)m * LL + p] = (__bf16)v;
}

// ---- W[m,q] = sum_p Abf[m][p]*scoreT[q][p]; plain stores (no atomics) ----
__global__ __launch_bounds__(256) void k_gemm_W_mfma(float* __restrict__ ws) {
    int bz = blockIdx.z;
    const __bf16* Ab = (const __bf16*)(ws + (size_t)bz * SLAB);
    const __bf16* Bb = (const __bf16*)(ws + (size_t)bz * SLAB + OFF_A);
    float* Wb = ws + (size_t)bz * SLAB + OFF_W;
    int m0 = blockIdx.y * 128, n0 = blockIdx.x * 128;
    __shared__ __align__(16) __bf16 As[128 * 64];
    __shared__ __align__(16) __bf16 Bs[128 * 64];
    f32x4 acc[4][4];
#pragma unroll
    for (int i = 0; i < 4; i++)
#pragma unroll
        for (int j = 0; j < 4; j++) acc[i][j] = (f32x4)0.0f;
    gemm_core<LL>(Ab, Bb, LL, LL, m0, n0, As, Bs, acc);
    int lane = threadIdx.x & 63, w = threadIdx.x >> 6;
    int lm = lane & 15, kgf = lane >> 4;
    int wm = (w & 1) * 64, wn = (w >> 1) * 64;
#pragma unroll
    for (int i = 0; i < 4; i++) {
#pragma unroll
        for (int r = 0; r < 4; r++) {
            int m = m0 + wm + i * 16 + kgf * 4 + r;
            float* dst = Wb + (size_t)m * LL + n0 + wn + lm;
#pragma unroll
            for (int j = 0; j < 4; j++)
                dst[j * 16] = acc[i][j][r];
        }
    }
}

// ---- gather: out[c,oy,ox] = 0.25 * sum of <=4 W taps (one store each) ----
__global__ __launch_bounds__(256) void k_gather(const float* __restrict__ ws,
                                                float* __restrict__ outp,
                                                int b0) {
    int t = blockIdx.x * 256 + threadIdx.x;   // Gc * 524288 threads
    int ox = t & 63, oy = (t >> 6) & 63, c = (t >> 12) & 127, bz = t >> 19;
    const float* Wb = ws + (size_t)bz * SLAB + OFF_W;
    // y candidates: even oy -> (jy=1, qy=oy/2); odd oy -> (jy=0, qy=(oy+1)/2) and (jy=2, qy=(oy-1)/2)
    int qyA = (oy + 1) >> 1;
    int jyA = (oy & 1) ? 0 : 1;
    int vA  = (qyA < 32);
    int qyB = (oy - 1) >> 1;
    int vB  = (oy & 1);
    int qxA = (ox + 1) >> 1;
    int jxA = (ox & 1) ? 0 : 1;
    int uA  = (qxA < 32);
    int qxB = (ox - 1) >> 1;
    int uB  = (ox & 1);
    const float* base = Wb + (size_t)c * 9 * LL;
    float s = 0.f;
    if (vA && uA) s += base[(size_t)(jyA * 3 + jxA) * LL + qyA * 32 + qxA];
    if (vA && uB) s += base[(size_t)(jyA * 3 + 2)   * LL + qyA * 32 + qxB];
    if (vB && uA) s += base[(size_t)(2 * 3 + jxA)   * LL + qyB * 32 + qxA];
    if (vB && uB) s += base[(size_t)(2 * 3 + 2)     * LL + qyB * 32 + qxB];
    outp[((size_t)((b0 + bz) * CC + c) * HH + oy) * WWI + ox] = 0.25f * s;
}

extern "C" void kernel_launch(void* const* d_in, const int* in_sizes, int n_in,
                              void* d_out, int out_size, void* d_ws, size_t ws_size,
                              hipStream_t stream) {
    (void)in_sizes; (void)n_in; (void)out_size;
    const float* f_o  = (const float*)d_in[0];
    const float* b_o  = (const float*)d_in[1];
    const float* mask = (const float*)d_in[2];
    float* out = (float*)d_out;

    int G = (int)(ws_size / (SLAB * sizeof(float)));   // ~10.76 MB per batch slab
    if (G < 1) G = 1;
    if (G > NB) G = NB;
    float* ws = (float*)d_ws;

    for (int b0 = 0; b0 < NB; b0 += G) {
        int Gc = NB - b0 < G ? NB - b0 : G;
        k_prep<<<dim3(Gc * 512), 256, 0, stream>>>(f_o, b_o, ws, b0);
        k_n2<<<dim3(Gc * 4), 256, 0, stream>>>(ws);
        k_bnorm_valid<<<dim3(Gc * 4), 256, 0, stream>>>(ws, mask, b0);
        k_gemm_T_mfma<<<dim3(8, 8, Gc), 256, 0, stream>>>(ws);
        k_st1<<<dim3(1024, 1, Gc), 256, 0, stream>>>(ws);
        k_st2<<<dim3(1024, 1, Gc), 256, 0, stream>>>(ws);
        k_st3t<<<dim3(16, 16, Gc), 256, 0, stream>>>(ws);
        k_softmax_bf<<<dim3(256, 1, Gc), 256, 0, stream>>>(ws);
        k_makeA<<<dim3(4608, 1, Gc), 256, 0, stream>>>(b_o, ws, b0);
        k_gemm_W_mfma<<<dim3(8, 9, Gc), 256, 0, stream>>>(ws);
        k_gather<<<dim3(Gc * 2048), 256, 0, stream>>>(ws, out, b0);
    }
}

// Round 5
// 413.011 us; speedup vs baseline: 4.2962x; 1.2020x over previous
//
#include <hip/hip_runtime.h>
#include <cmath>

#define CC 128
#define HH 64
#define WWI 64
#define LL 1024
#define NB 16
#define MM 1152          // 128 channels * 9 taps
#define KC 384           // concat K for bf16x3 T-GEMM
#define TPD 1156         // 34*34 padded dim

// per-batch slab layout (floats):
//  OFF_TP   [0, 1336336)         padded T (1156x1156); later S3T [0,1048576); later W [0,1179648)
//  OFF_S2   [1336336, 2384912)   S2; later scoreT (bf16 x 1M = 524288 fl)
//  OFF_POOL [2384912, 2974736)   bcat+fcat (bf16 x 1179648); later Abf
//  small    [2974736, 2977808)   n2 / bnorm / valid
#define SLAB      2977808ul
#define OFF_TP    0
#define OFF_S3T   0
#define OFF_W     0
#define OFF_S2    1336336
#define OFF_SCORET 1336336
#define OFF_POOL  2384912
#define OFF_N2    2974736
#define OFF_BNORM 2975760
#define OFF_VALID 2976784

typedef __bf16 bf16x8 __attribute__((ext_vector_type(8)));
typedef __bf16 bf16x4 __attribute__((ext_vector_type(4)));
typedef float f32x4 __attribute__((ext_vector_type(4)));

#define GLDS(g, l) __builtin_amdgcn_global_load_lds( \
    (const __attribute__((address_space(1))) unsigned int*)(const void*)(g), \
    (__attribute__((address_space(3))) unsigned int*)(void*)(l), 16, 0, 0)

// ---- downsample + transpose (LDS tile) + bf16 hi/lo concat + fused n2 ----
__global__ __launch_bounds__(256) void k_prep(const float* __restrict__ f_o,
                                              const float* __restrict__ b_o,
                                              float* __restrict__ ws,
                                              int b0) {
    int bz = blockIdx.y, gb = b0 + bz;
    int uy = blockIdx.x;                       // 32 blocks per batch
    __shared__ float lf[128 * 33];
    __shared__ float lb[128 * 33];
    __shared__ float red[8 * 32];
    int tid = threadIdx.x;
    int ux = tid & 31, co = tid >> 5;          // co in [0,8)
    size_t pix = (size_t)(2 * uy) * WWI + 2 * ux;
    const float* fbp = f_o + (size_t)gb * CC * HH * WWI + pix;
    const float* bbp = b_o + (size_t)gb * CC * HH * WWI + pix;
#pragma unroll
    for (int pass = 0; pass < 16; pass++) {
        int c = pass * 8 + co;
        lf[c * 33 + ux] = fbp[(size_t)c * HH * WWI];
        lb[c * 33 + ux] = bbp[(size_t)c * HH * WWI];
    }
    __syncthreads();
    int ux2 = tid >> 3, cg = (tid & 7) * 16;
    int u = uy * 32 + ux2;
    __bf16* bcat = (__bf16*)(ws + (size_t)bz * SLAB + OFF_POOL) + (size_t)u * KC;
    __bf16* fcat = bcat + 393216;
    float s2 = 0.f;
#pragma unroll
    for (int k = 0; k < 16; k++) {
        int c = cg + k;
        float fv = lf[c * 33 + ux2];
        float bv = lb[c * 33 + ux2];
        __bf16 fhi = (__bf16)fv; __bf16 flo = (__bf16)(fv - (float)fhi);
        __bf16 bhi = (__bf16)bv; __bf16 blo = (__bf16)(bv - (float)bhi);
        bcat[c] = bhi; bcat[128 + c] = bhi; bcat[256 + c] = blo;
        fcat[c] = fhi; fcat[128 + c] = flo; fcat[256 + c] = fhi;
        s2 += bv * bv;
    }
    red[(tid & 7) * 32 + ux2] = s2;
    __syncthreads();
    if (tid < 32) {
        float s = 0.f;
#pragma unroll
        for (int k = 0; k < 8; k++) s += red[k * 32 + tid];
        ws[(size_t)bz * SLAB + OFF_N2 + uy * 32 + tid] = s;
    }
}

__global__ __launch_bounds__(256) void k_bnorm_valid(float* __restrict__ ws,
                                                     const float* __restrict__ mask,
                                                     int b0) {
    int t = blockIdx.x * 256 + threadIdx.x;
    int p  = t & (LL - 1);
    int bz = t >> 10;
    int gb = b0 + bz;
    int py = p >> 5, px = p & 31;
    const float* mb = mask + (size_t)gb * HH * WWI;
    const float* n2 = ws + (size_t)bz * SLAB + OFF_N2;
    float s = 0.f, msum = 0.f;
#pragma unroll
    for (int dy = -1; dy <= 1; dy++) {
#pragma unroll
        for (int dx = -1; dx <= 1; dx++) {
            int py2 = py + dy, px2 = px + dx;
            if ((unsigned)py2 < 32u && (unsigned)px2 < 32u) {
                s    += n2[(py2 << 5) | px2];
                msum += mb[(2 * py2) * WWI + 2 * px2];
            }
        }
    }
    ws[(size_t)bz * SLAB + OFF_BNORM + p] = fmaxf(sqrtf(s), 1e-4f);
    ws[(size_t)bz * SLAB + OFF_VALID + p] = (msum == 0.0f) ? 1.0f : 0.0f;
}

// ---- zero the 4D-pad halo of Tp (interior written by gemm_T) ----
__global__ __launch_bounds__(256) void k_zerohalo(float* __restrict__ ws) {
    int bz = blockIdx.y;
    int R  = blockIdx.x;                       // [0,1156)
    float* Tr = ws + (size_t)bz * SLAB + OFF_TP + (size_t)R * TPD;
    int a = R / 34, b = R - 34 * a;
    bool rowhalo = (a == 0) | (a == 33) | (b == 0) | (b == 33);
    for (int c = threadIdx.x; c < TPD; c += 256) {
        int cy = c / 34, cb = c - 34 * cy;
        if (rowhalo | (cy == 0) | (cy == 33) | (cb == 0) | (cb == 33))
            Tr[c] = 0.f;
    }
}

// ---- shared 128x128-tile BK=64 MFMA GEMM core ----
template<int KTOT>
__device__ __forceinline__ void gemm_core(const __bf16* __restrict__ Ab,
                                          const __bf16* __restrict__ Bb,
                                          int lda, int ldb, int m0, int n0,
                                          __bf16* As, __bf16* Bs,
                                          f32x4 acc[4][4]) {
    int t = threadIdx.x;
    int lane = t & 63, w = t >> 6;
    int rsub = lane >> 3;
    int g8   = ((lane & 7) ^ (rsub & 7)) * 8;
    int lm = lane & 15, kgf = lane >> 4;
    int wm = (w & 1) * 64, wn = (w >> 1) * 64;

    for (int k0 = 0; k0 < KTOT; k0 += 64) {
        __syncthreads();
#pragma unroll
        for (int ci = 0; ci < 4; ci++) {
            int rb = ci * 32 + w * 8;
            int r  = rb + rsub;
            GLDS(Ab + (size_t)(m0 + r) * lda + k0 + g8, &As[rb * 64]);
            GLDS(Bb + (size_t)(n0 + r) * ldb + k0 + g8, &Bs[rb * 64]);
        }
        __syncthreads();
#pragma unroll
        for (int s2 = 0; s2 < 2; s2++) {
            bf16x8 af[4], bfr[4];
#pragma unroll
            for (int i = 0; i < 4; i++)
                af[i] = *(const bf16x8*)&As[(wm + i * 16 + lm) * 64 + (((s2 * 4 + kgf) ^ (lm & 7)) * 8)];
#pragma unroll
            for (int j = 0; j < 4; j++)
                bfr[j] = *(const bf16x8*)&Bs[(wn + j * 16 + lm) * 64 + (((s2 * 4 + kgf) ^ (lm & 7)) * 8)];
#pragma unroll
            for (int i = 0; i < 4; i++)
#pragma unroll
                for (int j = 0; j < 4; j++)
                    acc[i][j] = __builtin_amdgcn_mfma_f32_16x16x32_bf16(af[i], bfr[j], acc[i][j], 0, 0, 0);
        }
    }
}

// ---- T GEMM (bf16x3 == fp32), epilogue writes into padded-4D Tp ----
__global__ __launch_bounds__(256) void k_gemm_T_mfma(float* __restrict__ ws) {
    int bz = blockIdx.z;
    const __bf16* Ab = (const __bf16*)(ws + (size_t)bz * SLAB + OFF_POOL);
    const __bf16* Bb = Ab + 393216;
    float* Tp = ws + (size_t)bz * SLAB + OFF_TP;
    int m0 = blockIdx.y * 128, n0 = blockIdx.x * 128;
    __shared__ __align__(16) __bf16 As[128 * 64];
    __shared__ __align__(16) __bf16 Bs[128 * 64];
    f32x4 acc[4][4];
#pragma unroll
    for (int i = 0; i < 4; i++)
#pragma unroll
        for (int j = 0; j < 4; j++) acc[i][j] = (f32x4)0.0f;
    gemm_core<KC>(Ab, Bb, KC, KC, m0, n0, As, Bs, acc);
    int lane = threadIdx.x & 63, w = threadIdx.x >> 6;
    int lm = lane & 15, kgf = lane >> 4;
    int wm = (w & 1) * 64, wn = (w >> 1) * 64;
#pragma unroll
    for (int i = 0; i < 4; i++) {
#pragma unroll
        for (int r = 0; r < 4; r++) {
            int m = m0 + wm + i * 16 + kgf * 4 + r;
            float* dst = Tp + (size_t)(((m >> 5) + 1) * 34 + (m & 31) + 1) * TPD;
#pragma unroll
            for (int j = 0; j < 4; j++) {
                int v = n0 + wn + j * 16 + lm;
                dst[((v >> 5) + 1) * 34 + (v & 31) + 1] = acc[i][j][r];
            }
        }
    }
}

// ---- fused st1+st2: S2[i][j] = sum_k1 flatmask * inv[i+k1] * diag9(Tp; i+k1, j+k1) ----
__global__ __launch_bounds__(256) void k_s12(float* __restrict__ ws) {
    int bz = blockIdx.y;
    int i0 = blockIdx.x * 8;
    const float* Tp = ws + (size_t)bz * SLAB + OFF_TP;
    const float* bn = ws + (size_t)bz * SLAB + OFF_BNORM;
    float* S2 = ws + (size_t)bz * SLAB + OFF_S2;
    __shared__ float Dsh[10][1024];
    int tid = threadIdx.x;
    for (int rl = 0; rl < 10; rl++) {
        int r = i0 - 1 + rl;
        if ((unsigned)r >= 1024u) continue;    // never read (flat mask below)
        float invr = 1.0f / bn[r];
        size_t rbase = (size_t)(((r >> 5) + 1) * 34 + (r & 31) + 1) * TPD;
#pragma unroll
        for (int so = 0; so < 4; so++) {
            int s = so * 256 + tid;
            const float* cb = Tp + rbase + ((s >> 5) + 1) * 34 + (s & 31) + 1;
            float d = 0.f;
#pragma unroll
            for (int dy = -1; dy <= 1; dy++)
#pragma unroll
                for (int dx = -1; dx <= 1; dx++)
                    d += cb[dy * (34 * TPD + 34) + dx * (TPD + 1)];
            Dsh[rl][s] = d * invr;
        }
    }
    __syncthreads();
#pragma unroll
    for (int il = 0; il < 8; il++) {
        int i = i0 + il;
        float* orow = S2 + (size_t)i * LL;
#pragma unroll
        for (int jo = 0; jo < 4; jo++) {
            int j = jo * 256 + tid;
            float acc = 0.f;
#pragma unroll
            for (int k1 = -1; k1 <= 1; k1++) {
                int r = i + k1, s = j + k1;
                if ((unsigned)r < 1024u && (unsigned)s < 1024u)
                    acc += Dsh[il + 1 + k1][s];
            }
            orow[j] = acc;
        }
    }
}

// ---- second diag_fuse (sigma-space) fused with transpose: S3T[q][p] ----
__global__ __launch_bounds__(256) void k_st3t(float* __restrict__ ws) {
    int bz = blockIdx.z;
    const float* ib = ws + (size_t)bz * SLAB + OFF_S2;
    float* ob = ws + (size_t)bz * SLAB + OFF_S3T;
    int p0 = blockIdx.y * 64, q0 = blockIdx.x * 64;
    __shared__ float tile[64][65];
    int t = threadIdx.x;
#pragma unroll
    for (int it = 0; it < 16; it++) {
        int e = it * 256 + t;
        int pl = e >> 6, ql = e & 63;
        int p = p0 + pl, q = q0 + ql;
        int sp = ((p & 31) << 5) | (p >> 5);
        int sq = ((q & 31) << 5) | (q >> 5);
        float acc = 0.f;
#pragma unroll
        for (int k = -1; k <= 1; k++) {
            int tp = sp + k, tq = sq + k;
            if ((unsigned)tp < 1024u && (unsigned)tq < 1024u) {
                int row = ((tp & 31) << 5) | (tp >> 5);
                int col = ((tq & 31) << 5) | (tq >> 5);
                acc += ib[(size_t)row * LL + col];
            }
        }
        tile[pl][ql] = acc;
    }
    __syncthreads();
#pragma unroll
    for (int it = 0; it < 16; it++) {
        int e = it * 256 + t;
        int ql = e >> 6, pl = e & 63;
        ob[(size_t)(q0 + ql) * LL + p0 + pl] = tile[pl][ql];
    }
}

// ---- row softmax on S3T (contiguous over p), writes bf16 scoreT[q][p] ----
__global__ __launch_bounds__(256) void k_softmax_bf(float* __restrict__ ws) {
    int bz = blockIdx.z;
    int lane = threadIdx.x & 63;
    int q = blockIdx.x * 4 + (threadIdx.x >> 6);
    const float* row = ws + (size_t)bz * SLAB + OFF_S3T + (size_t)q * LL;
    const float* vb  = ws + (size_t)bz * SLAB + OFF_VALID;
    __bf16* orow = (__bf16*)(ws + (size_t)bz * SLAB + OFF_SCORET) + (size_t)q * LL;

    float4 v[4], vl[4];
#pragma unroll
    for (int i = 0; i < 4; i++) {
        int p = lane * 4 + i * 256;
        float4 s = *(const float4*)(row + p);
        float4 m = *(const float4*)(vb + p);
        v[i] = {s.x * m.x, s.y * m.y, s.z * m.z, s.w * m.w};
        vl[i] = m;
    }
    float mx = -1e30f;
#pragma unroll
    for (int i = 0; i < 4; i++)
        mx = fmaxf(mx, fmaxf(fmaxf(v[i].x, v[i].y), fmaxf(v[i].z, v[i].w)));
#pragma unroll
    for (int k = 1; k < 64; k <<= 1)
        mx = fmaxf(mx, __shfl_xor(mx, k, 64));
    float sum = 0.f;
    float4 e[4];
#pragma unroll
    for (int i = 0; i < 4; i++) {
        e[i].x = __expf(10.f * (v[i].x - mx));
        e[i].y = __expf(10.f * (v[i].y - mx));
        e[i].z = __expf(10.f * (v[i].z - mx));
        e[i].w = __expf(10.f * (v[i].w - mx));
        sum += e[i].x + e[i].y + e[i].z + e[i].w;
    }
#pragma unroll
    for (int k = 1; k < 64; k <<= 1)
        sum += __shfl_xor(sum, k, 64);
    float inv = 1.0f / sum;
#pragma unroll
    for (int i = 0; i < 4; i++) {
        bf16x4 o;
        o[0] = (__bf16)(e[i].x * inv * vl[i].x);
        o[1] = (__bf16)(e[i].y * inv * vl[i].y);
        o[2] = (__bf16)(e[i].z * inv * vl[i].z);
        o[3] = (__bf16)(e[i].w * inv * vl[i].w);
        *(bf16x4*)(orow + lane * 4 + i * 256) = o;
    }
}

// ---- materialize A_bf16[m=(c,jy,jx)][p] over dead bcat/fcat ----
__global__ __launch_bounds__(256) void k_makeA(const float* __restrict__ b_o,
                                               float* __restrict__ ws,
                                               int b0) {
    int bz = blockIdx.z, gb = b0 + bz;
    int e = blockIdx.x * 256 + threadIdx.x;
    int m = e >> 10, p = e & 1023;
    int c = m / 9, rem = m - 9 * c, jy = rem / 3, jx = rem - 3 * jy;
    int row = 2 * (p >> 5) + jy - 1;
    int col = 2 * (p & 31) + jx - 1;
    float v = 0.f;
    if ((unsigned)row < 64u && (unsigned)col < 64u)
        v = b_o[((size_t)(gb * CC + c) * HH + row) * WWI + col];
    ((__bf16*)(ws + (size_t)bz * SLAB + OFF_POOL))[(size_t)m * LL + p] = (__bf16)v;
}

// ---- W[m,q] = sum_p Abf[m][p]*scoreT[q][p]; plain stores ----
__global__ __launch_bounds__(256) void k_gemm_W_mfma(float* __restrict__ ws) {
    int bz = blockIdx.z;
    const __bf16* Ab = (const __bf16*)(ws + (size_t)bz * SLAB + OFF_POOL);
    const __bf16* Bb = (const __bf16*)(ws + (size_t)bz * SLAB + OFF_SCORET);
    float* Wb = ws + (size_t)bz * SLAB + OFF_W;
    int m0 = blockIdx.y * 128, n0 = blockIdx.x * 128;
    __shared__ __align__(16) __bf16 As[128 * 64];
    __shared__ __align__(16) __bf16 Bs[128 * 64];
    f32x4 acc[4][4];
#pragma unroll
    for (int i = 0; i < 4; i++)
#pragma unroll
        for (int j = 0; j < 4; j++) acc[i][j] = (f32x4)0.0f;
    gemm_core<LL>(Ab, Bb, LL, LL, m0, n0, As, Bs, acc);
    int lane = threadIdx.x & 63, w = threadIdx.x >> 6;
    int lm = lane & 15, kgf = lane >> 4;
    int wm = (w & 1) * 64, wn = (w >> 1) * 64;
#pragma unroll
    for (int i = 0; i < 4; i++) {
#pragma unroll
        for (int r = 0; r < 4; r++) {
            int m = m0 + wm + i * 16 + kgf * 4 + r;
            float* dst = Wb + (size_t)m * LL + n0 + wn + lm;
#pragma unroll
            for (int j = 0; j < 4; j++)
                dst[j * 16] = acc[i][j][r];
        }
    }
}

// ---- gather: out[c,oy,ox] = 0.25 * sum of <=4 W taps ----
__global__ __launch_bounds__(256) void k_gather(const float* __restrict__ ws,
                                                float* __restrict__ outp,
                                                int b0) {
    int t = blockIdx.x * 256 + threadIdx.x;
    int ox = t & 63, oy = (t >> 6) & 63, c = (t >> 12) & 127, bz = t >> 19;
    const float* Wb = ws + (size_t)bz * SLAB + OFF_W;
    int qyA = (oy + 1) >> 1;
    int jyA = (oy & 1) ? 0 : 1;
    int vA  = (qyA < 32);
    int qyB = (oy - 1) >> 1;
    int vB  = (oy & 1);
    int qxA = (ox + 1) >> 1;
    int jxA = (ox & 1) ? 0 : 1;
    int uA  = (qxA < 32);
    int qxB = (ox - 1) >> 1;
    int uB  = (ox & 1);
    const float* base = Wb + (size_t)c * 9 * LL;
    float s = 0.f;
    if (vA && uA) s += base[(size_t)(jyA * 3 + jxA) * LL + qyA * 32 + qxA];
    if (vA && uB) s += base[(size_t)(jyA * 3 + 2)   * LL + qyA * 32 + qxB];
    if (vB && uA) s += base[(size_t)(2 * 3 + jxA)   * LL + qyB * 32 + qxA];
    if (vB && uB) s += base[(size_t)(2 * 3 + 2)     * LL + qyB * 32 + qxB];
    outp[((size_t)((b0 + bz) * CC + c) * HH + oy) * WWI + ox] = 0.25f * s;
}

extern "C" void kernel_launch(void* const* d_in, const int* in_sizes, int n_in,
                              void* d_out, int out_size, void* d_ws, size_t ws_size,
                              hipStream_t stream) {
    (void)in_sizes; (void)n_in; (void)out_size;
    const float* f_o  = (const float*)d_in[0];
    const float* b_o  = (const float*)d_in[1];
    const float* mask = (const float*)d_in[2];
    float* out = (float*)d_out;

    int G = (int)(ws_size / (SLAB * sizeof(float)));   // ~11.4 MB per batch slab
    if (G < 1) G = 1;
    if (G > NB) G = NB;
    float* ws = (float*)d_ws;

    for (int b0 = 0; b0 < NB; b0 += G) {
        int Gc = NB - b0 < G ? NB - b0 : G;
        k_prep<<<dim3(32, Gc), 256, 0, stream>>>(f_o, b_o, ws, b0);
        k_bnorm_valid<<<dim3(Gc * 4), 256, 0, stream>>>(ws, mask, b0);
        k_zerohalo<<<dim3(TPD, Gc), 256, 0, stream>>>(ws);
        k_gemm_T_mfma<<<dim3(8, 8, Gc), 256, 0, stream>>>(ws);
        k_s12<<<dim3(128, Gc), 256, 0, stream>>>(ws);
        k_st3t<<<dim3(16, 16, Gc), 256, 0, stream>>>(ws);
        k_softmax_bf<<<dim3(256, 1, Gc), 256, 0, stream>>>(ws);
        k_makeA<<<dim3(4608, 1, Gc), 256, 0, stream>>>(b_o, ws, b0);
        k_gemm_W_mfma<<<dim3(8, 9, Gc), 256, 0, stream>>>(ws);
        k_gather<<<dim3(Gc * 2048), 256, 0, stream>>>(ws, out, b0);
    }
}

// Round 6
// 373.604 us; speedup vs baseline: 4.7494x; 1.1055x over previous
//
#include <hip/hip_runtime.h>
#include <cmath>

#define CC 128
#define HH 64
#define WWI 64
#define LL 1024
#define NB 16
#define MM 1152          // 128 channels * 9 taps
#define KC 384           // concat K for bf16x3 T-GEMM
#define TPD 1156         // 34*34 padded dim

// per-batch slab layout (floats):
//  OFF_TP   [0, 1336336)         padded T (1156x1156); later S3T [0,1048576); later W (bf16 x 1179648 = 589824 fl)
//  OFF_S2   [1336336, 2384912)   S2; later scoreT (bf16 x 1M = 524288 fl)
//  OFF_POOL [2384912, 2974736)   bcat+fcat (bf16 x 1179648); later Abf
//  small    [2974736, 2977808)   n2 / bnorm / valid
#define SLAB      2977808ul
#define OFF_TP    0
#define OFF_S3T   0
#define OFF_W     0
#define OFF_S2    1336336
#define OFF_SCORET 1336336
#define OFF_POOL  2384912
#define OFF_N2    2974736
#define OFF_BNORM 2975760
#define OFF_VALID 2976784

// halo geometry for compact zerohalo
#define NHROW 132                 // halo rows (a in {0,33} or b in {0,33})
#define NH1 (NHROW * TPD)         // full halo-row elements
#define NHALO (NH1 + 1024 * NHROW)

typedef __bf16 bf16x8 __attribute__((ext_vector_type(8)));
typedef __bf16 bf16x4 __attribute__((ext_vector_type(4)));
typedef float f32x4 __attribute__((ext_vector_type(4)));

#define GLDS(g, l) __builtin_amdgcn_global_load_lds( \
    (const __attribute__((address_space(1))) unsigned int*)(const void*)(g), \
    (__attribute__((address_space(3))) unsigned int*)(void*)(l), 16, 0, 0)

// ---- downsample + transpose (LDS tile) + bf16 hi/lo concat + fused n2 ----
__global__ __launch_bounds__(256) void k_prep(const float* __restrict__ f_o,
                                              const float* __restrict__ b_o,
                                              float* __restrict__ ws,
                                              int b0) {
    int bz = blockIdx.y, gb = b0 + bz;
    int uy = blockIdx.x;
    __shared__ float lf[128 * 33];
    __shared__ float lb[128 * 33];
    __shared__ float red[8 * 32];
    int tid = threadIdx.x;
    int ux = tid & 31, co = tid >> 5;
    size_t pix = (size_t)(2 * uy) * WWI + 2 * ux;
    const float* fbp = f_o + (size_t)gb * CC * HH * WWI + pix;
    const float* bbp = b_o + (size_t)gb * CC * HH * WWI + pix;
#pragma unroll
    for (int pass = 0; pass < 16; pass++) {
        int c = pass * 8 + co;
        lf[c * 33 + ux] = fbp[(size_t)c * HH * WWI];
        lb[c * 33 + ux] = bbp[(size_t)c * HH * WWI];
    }
    __syncthreads();
    int ux2 = tid >> 3, cg = (tid & 7) * 16;
    int u = uy * 32 + ux2;
    __bf16* bcat = (__bf16*)(ws + (size_t)bz * SLAB + OFF_POOL) + (size_t)u * KC;
    __bf16* fcat = bcat + 393216;
    float s2 = 0.f;
#pragma unroll
    for (int k = 0; k < 16; k++) {
        int c = cg + k;
        float fv = lf[c * 33 + ux2];
        float bv = lb[c * 33 + ux2];
        __bf16 fhi = (__bf16)fv; __bf16 flo = (__bf16)(fv - (float)fhi);
        __bf16 bhi = (__bf16)bv; __bf16 blo = (__bf16)(bv - (float)bhi);
        bcat[c] = bhi; bcat[128 + c] = bhi; bcat[256 + c] = blo;
        fcat[c] = fhi; fcat[128 + c] = flo; fcat[256 + c] = fhi;
        s2 += bv * bv;
    }
    red[(tid & 7) * 32 + ux2] = s2;
    __syncthreads();
    if (tid < 32) {
        float s = 0.f;
#pragma unroll
        for (int k = 0; k < 8; k++) s += red[k * 32 + tid];
        ws[(size_t)bz * SLAB + OFF_N2 + uy * 32 + tid] = s;
    }
}

__global__ __launch_bounds__(256) void k_bnorm_valid(float* __restrict__ ws,
                                                     const float* __restrict__ mask,
                                                     int b0) {
    int t = blockIdx.x * 256 + threadIdx.x;
    int p  = t & (LL - 1);
    int bz = t >> 10;
    int gb = b0 + bz;
    int py = p >> 5, px = p & 31;
    const float* mb = mask + (size_t)gb * HH * WWI;
    const float* n2 = ws + (size_t)bz * SLAB + OFF_N2;
    float s = 0.f, msum = 0.f;
#pragma unroll
    for (int dy = -1; dy <= 1; dy++) {
#pragma unroll
        for (int dx = -1; dx <= 1; dx++) {
            int py2 = py + dy, px2 = px + dx;
            if ((unsigned)py2 < 32u && (unsigned)px2 < 32u) {
                s    += n2[(py2 << 5) | px2];
                msum += mb[(2 * py2) * WWI + 2 * px2];
            }
        }
    }
    ws[(size_t)bz * SLAB + OFF_BNORM + p] = fmaxf(sqrtf(s), 1e-4f);
    ws[(size_t)bz * SLAB + OFF_VALID + p] = (msum == 0.0f) ? 1.0f : 0.0f;
}

// map k in [0,132) to halo row/col index in [0,1156)
__device__ __forceinline__ int halo_idx(int k) {
    if (k < 34) return k;
    if (k < 68) return 1122 + (k - 34);
    if (k < 100) return 34 * (k - 100 + 33);      // b==0: R = 34*a, a in [1,32]
    return 34 * (k - 132 + 33) + 33;              // b==33
}

// ---- zero ONLY the halo elements of Tp ----
__global__ __launch_bounds__(256) void k_zerohalo(float* __restrict__ ws) {
    int bz = blockIdx.y;
    int t = blockIdx.x * 256 + threadIdx.x;
    if (t >= NHALO) return;
    float* Tp = ws + (size_t)bz * SLAB + OFF_TP;
    if (t < NH1) {
        int R = halo_idx(t / TPD);
        Tp[(size_t)R * TPD + (t % TPD)] = 0.f;
    } else {
        int t2 = t - NH1;
        int ir = t2 / NHROW;                       // interior row index [0,1024)
        int R  = 34 * (1 + (ir >> 5)) + 1 + (ir & 31);
        int C  = halo_idx(t2 % NHROW);
        Tp[(size_t)R * TPD + C] = 0.f;
    }
}

// ---- shared 128x128-tile BK=64 MFMA GEMM core ----
template<int KTOT>
__device__ __forceinline__ void gemm_core(const __bf16* __restrict__ Ab,
                                          const __bf16* __restrict__ Bb,
                                          int lda, int ldb, int m0, int n0,
                                          __bf16* As, __bf16* Bs,
                                          f32x4 acc[4][4]) {
    int t = threadIdx.x;
    int lane = t & 63, w = t >> 6;
    int rsub = lane >> 3;
    int g8   = ((lane & 7) ^ (rsub & 7)) * 8;
    int lm = lane & 15, kgf = lane >> 4;
    int wm = (w & 1) * 64, wn = (w >> 1) * 64;

    for (int k0 = 0; k0 < KTOT; k0 += 64) {
        __syncthreads();
#pragma unroll
        for (int ci = 0; ci < 4; ci++) {
            int rb = ci * 32 + w * 8;
            int r  = rb + rsub;
            GLDS(Ab + (size_t)(m0 + r) * lda + k0 + g8, &As[rb * 64]);
            GLDS(Bb + (size_t)(n0 + r) * ldb + k0 + g8, &Bs[rb * 64]);
        }
        __syncthreads();
#pragma unroll
        for (int s2 = 0; s2 < 2; s2++) {
            bf16x8 af[4], bfr[4];
#pragma unroll
            for (int i = 0; i < 4; i++)
                af[i] = *(const bf16x8*)&As[(wm + i * 16 + lm) * 64 + (((s2 * 4 + kgf) ^ (lm & 7)) * 8)];
#pragma unroll
            for (int j = 0; j < 4; j++)
                bfr[j] = *(const bf16x8*)&Bs[(wn + j * 16 + lm) * 64 + (((s2 * 4 + kgf) ^ (lm & 7)) * 8)];
#pragma unroll
            for (int i = 0; i < 4; i++)
#pragma unroll
                for (int j = 0; j < 4; j++)
                    acc[i][j] = __builtin_amdgcn_mfma_f32_16x16x32_bf16(af[i], bfr[j], acc[i][j], 0, 0, 0);
        }
    }
}

// ---- T GEMM (bf16x3 == fp32), padded-4D epilogue; XCD-affinity decode ----
// swz: blockIdx.x = batch lane (== dispatch id % 8 == XCD), z = (bhalf, n-tile)
__global__ __launch_bounds__(256) void k_gemm_T_mfma(float* __restrict__ ws, int swz) {
    int bz, m0, n0;
    if (swz) {
        bz = blockIdx.x + 8 * (blockIdx.z & 1);
        m0 = blockIdx.y * 128;
        n0 = (blockIdx.z >> 1) * 128;
    } else {
        bz = blockIdx.z; m0 = blockIdx.y * 128; n0 = blockIdx.x * 128;
    }
    const __bf16* Ab = (const __bf16*)(ws + (size_t)bz * SLAB + OFF_POOL);
    const __bf16* Bb = Ab + 393216;
    float* Tp = ws + (size_t)bz * SLAB + OFF_TP;
    __shared__ __align__(16) __bf16 As[128 * 64];
    __shared__ __align__(16) __bf16 Bs[128 * 64];
    f32x4 acc[4][4];
#pragma unroll
    for (int i = 0; i < 4; i++)
#pragma unroll
        for (int j = 0; j < 4; j++) acc[i][j] = (f32x4)0.0f;
    gemm_core<KC>(Ab, Bb, KC, KC, m0, n0, As, Bs, acc);
    int lane = threadIdx.x & 63, w = threadIdx.x >> 6;
    int lm = lane & 15, kgf = lane >> 4;
    int wm = (w & 1) * 64, wn = (w >> 1) * 64;
#pragma unroll
    for (int i = 0; i < 4; i++) {
#pragma unroll
        for (int r = 0; r < 4; r++) {
            int m = m0 + wm + i * 16 + kgf * 4 + r;
            float* dst = Tp + (size_t)(((m >> 5) + 1) * 34 + (m & 31) + 1) * TPD;
#pragma unroll
            for (int j = 0; j < 4; j++) {
                int v = n0 + wn + j * 16 + lm;
                dst[((v >> 5) + 1) * 34 + (v & 31) + 1] = acc[i][j][r];
            }
        }
    }
}

// ---- fused st1+st2 ----
__global__ __launch_bounds__(256) void k_s12(float* __restrict__ ws) {
    int bz = blockIdx.y;
    int i0 = blockIdx.x * 8;
    const float* Tp = ws + (size_t)bz * SLAB + OFF_TP;
    const float* bn = ws + (size_t)bz * SLAB + OFF_BNORM;
    float* S2 = ws + (size_t)bz * SLAB + OFF_S2;
    __shared__ float Dsh[10][1024];
    int tid = threadIdx.x;
    for (int rl = 0; rl < 10; rl++) {
        int r = i0 - 1 + rl;
        if ((unsigned)r >= 1024u) continue;
        float invr = 1.0f / bn[r];
        size_t rbase = (size_t)(((r >> 5) + 1) * 34 + (r & 31) + 1) * TPD;
#pragma unroll
        for (int so = 0; so < 4; so++) {
            int s = so * 256 + tid;
            const float* cb = Tp + rbase + ((s >> 5) + 1) * 34 + (s & 31) + 1;
            float d = 0.f;
#pragma unroll
            for (int dy = -1; dy <= 1; dy++)
#pragma unroll
                for (int dx = -1; dx <= 1; dx++)
                    d += cb[dy * (34 * TPD + 34) + dx * (TPD + 1)];
            Dsh[rl][s] = d * invr;
        }
    }
    __syncthreads();
#pragma unroll
    for (int il = 0; il < 8; il++) {
        int i = i0 + il;
        float* orow = S2 + (size_t)i * LL;
#pragma unroll
        for (int jo = 0; jo < 4; jo++) {
            int j = jo * 256 + tid;
            float acc = 0.f;
#pragma unroll
            for (int k1 = -1; k1 <= 1; k1++) {
                int r = i + k1, s = j + k1;
                if ((unsigned)r < 1024u && (unsigned)s < 1024u)
                    acc += Dsh[il + 1 + k1][s];
            }
            orow[j] = acc;
        }
    }
}

// ---- second diag_fuse (sigma-space) fused with transpose: S3T[q][p] ----
__global__ __launch_bounds__(256) void k_st3t(float* __restrict__ ws) {
    int bz = blockIdx.z;
    const float* ib = ws + (size_t)bz * SLAB + OFF_S2;
    float* ob = ws + (size_t)bz * SLAB + OFF_S3T;
    int p0 = blockIdx.y * 64, q0 = blockIdx.x * 64;
    __shared__ float tile[64][65];
    int t = threadIdx.x;
#pragma unroll
    for (int it = 0; it < 16; it++) {
        int e = it * 256 + t;
        int pl = e >> 6, ql = e & 63;
        int p = p0 + pl, q = q0 + ql;
        int sp = ((p & 31) << 5) | (p >> 5);
        int sq = ((q & 31) << 5) | (q >> 5);
        float acc = 0.f;
#pragma unroll
        for (int k = -1; k <= 1; k++) {
            int tp = sp + k, tq = sq + k;
            if ((unsigned)tp < 1024u && (unsigned)tq < 1024u) {
                int row = ((tp & 31) << 5) | (tp >> 5);
                int col = ((tq & 31) << 5) | (tq >> 5);
                acc += ib[(size_t)row * LL + col];
            }
        }
        tile[pl][ql] = acc;
    }
    __syncthreads();
#pragma unroll
    for (int it = 0; it < 16; it++) {
        int e = it * 256 + t;
        int ql = e >> 6, pl = e & 63;
        ob[(size_t)(q0 + ql) * LL + p0 + pl] = tile[pl][ql];
    }
}

// ---- row softmax on S3T, writes bf16 scoreT[q][p] ----
__global__ __launch_bounds__(256) void k_softmax_bf(float* __restrict__ ws) {
    int bz = blockIdx.z;
    int lane = threadIdx.x & 63;
    int q = blockIdx.x * 4 + (threadIdx.x >> 6);
    const float* row = ws + (size_t)bz * SLAB + OFF_S3T + (size_t)q * LL;
    const float* vb  = ws + (size_t)bz * SLAB + OFF_VALID;
    __bf16* orow = (__bf16*)(ws + (size_t)bz * SLAB + OFF_SCORET) + (size_t)q * LL;

    float4 v[4], vl[4];
#pragma unroll
    for (int i = 0; i < 4; i++) {
        int p = lane * 4 + i * 256;
        float4 s = *(const float4*)(row + p);
        float4 m = *(const float4*)(vb + p);
        v[i] = {s.x * m.x, s.y * m.y, s.z * m.z, s.w * m.w};
        vl[i] = m;
    }
    float mx = -1e30f;
#pragma unroll
    for (int i = 0; i < 4; i++)
        mx = fmaxf(mx, fmaxf(fmaxf(v[i].x, v[i].y), fmaxf(v[i].z, v[i].w)));
#pragma unroll
    for (int k = 1; k < 64; k <<= 1)
        mx = fmaxf(mx, __shfl_xor(mx, k, 64));
    float sum = 0.f;
    float4 e[4];
#pragma unroll
    for (int i = 0; i < 4; i++) {
        e[i].x = __expf(10.f * (v[i].x - mx));
        e[i].y = __expf(10.f * (v[i].y - mx));
        e[i].z = __expf(10.f * (v[i].z - mx));
        e[i].w = __expf(10.f * (v[i].w - mx));
        sum += e[i].x + e[i].y + e[i].z + e[i].w;
    }
#pragma unroll
    for (int k = 1; k < 64; k <<= 1)
        sum += __shfl_xor(sum, k, 64);
    float inv = 1.0f / sum;
#pragma unroll
    for (int i = 0; i < 4; i++) {
        bf16x4 o;
        o[0] = (__bf16)(e[i].x * inv * vl[i].x);
        o[1] = (__bf16)(e[i].y * inv * vl[i].y);
        o[2] = (__bf16)(e[i].z * inv * vl[i].z);
        o[3] = (__bf16)(e[i].w * inv * vl[i].w);
        *(bf16x4*)(orow + lane * 4 + i * 256) = o;
    }
}

// ---- coalesced makeA: block per (channel, batch); LDS image tile ----
__global__ __launch_bounds__(256) void k_makeA(const float* __restrict__ b_o,
                                               float* __restrict__ ws,
                                               int b0) {
    int c = blockIdx.x, bz = blockIdx.y, gb = b0 + bz;
    __shared__ float img[64][65];
    int t = threadIdx.x;
    const float4* src = (const float4*)(b_o + (size_t)(gb * CC + c) * HH * WWI);
#pragma unroll
    for (int it = 0; it < 4; it++) {
        int idx = it * 256 + t;                 // 1024 float4 = 64x64
        float4 v = src[idx];
        int row = idx >> 4, col4 = (idx & 15) * 4;
        img[row][col4] = v.x; img[row][col4 + 1] = v.y;
        img[row][col4 + 2] = v.z; img[row][col4 + 3] = v.w;
    }
    __syncthreads();
    __bf16* Ab = (__bf16*)(ws + (size_t)bz * SLAB + OFF_POOL) + (size_t)c * 9 * LL;
    int py = t >> 3, px4 = (t & 7) * 4;        // p = t*4 .. t*4+3
#pragma unroll
    for (int jy = 0; jy < 3; jy++) {
        int row = 2 * py + jy - 1;
        bool rok = (unsigned)row < 64u;
#pragma unroll
        for (int jx = 0; jx < 3; jx++) {
            bf16x4 o;
#pragma unroll
            for (int e = 0; e < 4; e++) {
                int col = 2 * (px4 + e) + jx - 1;
                float v = (rok && (unsigned)col < 64u) ? img[rok ? row : 0][(unsigned)col < 64u ? col : 0] : 0.f;
                o[e] = (__bf16)v;
            }
            *(bf16x4*)(Ab + (size_t)(jy * 3 + jx) * LL + t * 4) = o;
        }
    }
}

// ---- W[m,q] GEMM; bf16 W stores; XCD-affinity decode ----
__global__ __launch_bounds__(256) void k_gemm_W_mfma(float* __restrict__ ws, int swz) {
    int bz, m0, n0;
    if (swz) {
        bz = blockIdx.x + 8 * (blockIdx.z & 1);
        m0 = blockIdx.y * 128;
        n0 = (blockIdx.z >> 1) * 128;
    } else {
        bz = blockIdx.z; m0 = blockIdx.y * 128; n0 = blockIdx.x * 128;
    }
    const __bf16* Ab = (const __bf16*)(ws + (size_t)bz * SLAB + OFF_POOL);
    const __bf16* Bb = (const __bf16*)(ws + (size_t)bz * SLAB + OFF_SCORET);
    __bf16* Wb = (__bf16*)(ws + (size_t)bz * SLAB + OFF_W);
    __shared__ __align__(16) __bf16 As[128 * 64];
    __shared__ __align__(16) __bf16 Bs[128 * 64];
    f32x4 acc[4][4];
#pragma unroll
    for (int i = 0; i < 4; i++)
#pragma unroll
        for (int j = 0; j < 4; j++) acc[i][j] = (f32x4)0.0f;
    gemm_core<LL>(Ab, Bb, LL, LL, m0, n0, As, Bs, acc);
    int lane = threadIdx.x & 63, w = threadIdx.x >> 6;
    int lm = lane & 15, kgf = lane >> 4;
    int wm = (w & 1) * 64, wn = (w >> 1) * 64;
#pragma unroll
    for (int i = 0; i < 4; i++) {
#pragma unroll
        for (int r = 0; r < 4; r++) {
            int m = m0 + wm + i * 16 + kgf * 4 + r;
            __bf16* dst = Wb + (size_t)m * LL + n0 + wn + lm;
#pragma unroll
            for (int j = 0; j < 4; j++)
                dst[j * 16] = (__bf16)acc[i][j][r];
        }
    }
}

// ---- gather: out[c,oy,ox] = 0.25 * sum of <=4 bf16 W taps ----
__global__ __launch_bounds__(256) void k_gather(const float* __restrict__ ws,
                                                float* __restrict__ outp,
                                                int b0) {
    int t = blockIdx.x * 256 + threadIdx.x;
    int ox = t & 63, oy = (t >> 6) & 63, c = (t >> 12) & 127, bz = t >> 19;
    const __bf16* Wb = (const __bf16*)(ws + (size_t)bz * SLAB + OFF_W);
    int qyA = (oy + 1) >> 1;
    int jyA = (oy & 1) ? 0 : 1;
    int vA  = (qyA < 32);
    int qyB = (oy - 1) >> 1;
    int vB  = (oy & 1);
    int qxA = (ox + 1) >> 1;
    int jxA = (ox & 1) ? 0 : 1;
    int uA  = (qxA < 32);
    int qxB = (ox - 1) >> 1;
    int uB  = (ox & 1);
    const __bf16* base = Wb + (size_t)c * 9 * LL;
    float s = 0.f;
    if (vA && uA) s += (float)base[(size_t)(jyA * 3 + jxA) * LL + qyA * 32 + qxA];
    if (vA && uB) s += (float)base[(size_t)(jyA * 3 + 2)   * LL + qyA * 32 + qxB];
    if (vB && uA) s += (float)base[(size_t)(2 * 3 + jxA)   * LL + qyB * 32 + qxA];
    if (vB && uB) s += (float)base[(size_t)(2 * 3 + 2)     * LL + qyB * 32 + qxB];
    outp[((size_t)((b0 + bz) * CC + c) * HH + oy) * WWI + ox] = 0.25f * s;
}

extern "C" void kernel_launch(void* const* d_in, const int* in_sizes, int n_in,
                              void* d_out, int out_size, void* d_ws, size_t ws_size,
                              hipStream_t stream) {
    (void)in_sizes; (void)n_in; (void)out_size;
    const float* f_o  = (const float*)d_in[0];
    const float* b_o  = (const float*)d_in[1];
    const float* mask = (const float*)d_in[2];
    float* out = (float*)d_out;

    int G = (int)(ws_size / (SLAB * sizeof(float)));   // ~11.4 MB per batch slab
    if (G < 1) G = 1;
    if (G > NB) G = NB;
    float* ws = (float*)d_ws;

    for (int b0 = 0; b0 < NB; b0 += G) {
        int Gc = NB - b0 < G ? NB - b0 : G;
        int swz = (Gc == 16) ? 1 : 0;
        k_prep<<<dim3(32, Gc), 256, 0, stream>>>(f_o, b_o, ws, b0);
        k_bnorm_valid<<<dim3(Gc * 4), 256, 0, stream>>>(ws, mask, b0);
        k_zerohalo<<<dim3((NHALO + 255) / 256, Gc), 256, 0, stream>>>(ws);
        k_gemm_T_mfma<<<dim3(8, 8, Gc), 256, 0, stream>>>(ws, swz);
        k_s12<<<dim3(128, Gc), 256, 0, stream>>>(ws);
        k_st3t<<<dim3(16, 16, Gc), 256, 0, stream>>>(ws);
        k_softmax_bf<<<dim3(256, 1, Gc), 256, 0, stream>>>(ws);
        k_makeA<<<dim3(CC, Gc), 256, 0, stream>>>(b_o, ws, b0);
        k_gemm_W_mfma<<<dim3(8, 9, Gc), 256, 0, stream>>>(ws, swz);
        k_gather<<<dim3(Gc * 2048), 256, 0, stream>>>(ws, out, b0);
    }
}

// Round 7
// 371.437 us; speedup vs baseline: 4.7771x; 1.0058x over previous
//
#include <hip/hip_runtime.h>
#include <cmath>

#define CC 128
#define HH 64
#define WWI 64
#define LL 1024
#define NB 16
#define MM 1152          // 128 channels * 9 taps
#define KC 384           // concat K for bf16x3 T-GEMM
#define TPD 1156         // 34*34 padded dim

// per-batch slab layout (floats):
//  OFF_TP   [0, 1336336)         padded T (1156x1156); later S3T [0,1048576); later W (bf16 x 1179648 = 589824 fl)
//  OFF_S2   [1336336, 2384912)   S2; later scoreT (bf16 x 1M = 524288 fl)
//  OFF_POOL [2384912, 2974736)   bcat+fcat (bf16 x 1179648); later Abf
//  small    [2974736, 2977808)   n2 / bnorm / valid
#define SLAB      2977808ul
#define OFF_TP    0
#define OFF_S3T   0
#define OFF_W     0
#define OFF_S2    1336336
#define OFF_SCORET 1336336
#define OFF_POOL  2384912
#define OFF_N2    2974736
#define OFF_BNORM 2975760
#define OFF_VALID 2976784

// halo geometry for compact zerohalo
#define NHROW 132
#define NH1 (NHROW * TPD)
#define NHALO (NH1 + 1024 * NHROW)

typedef __bf16 bf16x8 __attribute__((ext_vector_type(8)));
typedef __bf16 bf16x4 __attribute__((ext_vector_type(4)));
typedef float f32x4 __attribute__((ext_vector_type(4)));

#define GLDS(g, l) __builtin_amdgcn_global_load_lds( \
    (const __attribute__((address_space(1))) unsigned int*)(const void*)(g), \
    (__attribute__((address_space(3))) unsigned int*)(void*)(l), 16, 0, 0)

// ---- downsample + transpose (LDS tile) + bf16 hi/lo concat + fused n2 ----
__global__ __launch_bounds__(256) void k_prep(const float* __restrict__ f_o,
                                              const float* __restrict__ b_o,
                                              float* __restrict__ ws,
                                              int b0) {
    int bz = blockIdx.y, gb = b0 + bz;
    int uy = blockIdx.x;
    __shared__ float lf[128 * 33];
    __shared__ float lb[128 * 33];
    __shared__ float red[8 * 32];
    int tid = threadIdx.x;
    int ux = tid & 31, co = tid >> 5;
    size_t pix = (size_t)(2 * uy) * WWI + 2 * ux;
    const float* fbp = f_o + (size_t)gb * CC * HH * WWI + pix;
    const float* bbp = b_o + (size_t)gb * CC * HH * WWI + pix;
#pragma unroll
    for (int pass = 0; pass < 16; pass++) {
        int c = pass * 8 + co;
        lf[c * 33 + ux] = fbp[(size_t)c * HH * WWI];
        lb[c * 33 + ux] = bbp[(size_t)c * HH * WWI];
    }
    __syncthreads();
    int ux2 = tid >> 3, cg = (tid & 7) * 16;
    int u = uy * 32 + ux2;
    __bf16* bcat = (__bf16*)(ws + (size_t)bz * SLAB + OFF_POOL) + (size_t)u * KC;
    __bf16* fcat = bcat + 393216;
    float s2 = 0.f;
#pragma unroll
    for (int k = 0; k < 16; k++) {
        int c = cg + k;
        float fv = lf[c * 33 + ux2];
        float bv = lb[c * 33 + ux2];
        __bf16 fhi = (__bf16)fv; __bf16 flo = (__bf16)(fv - (float)fhi);
        __bf16 bhi = (__bf16)bv; __bf16 blo = (__bf16)(bv - (float)bhi);
        bcat[c] = bhi; bcat[128 + c] = bhi; bcat[256 + c] = blo;
        fcat[c] = fhi; fcat[128 + c] = flo; fcat[256 + c] = fhi;
        s2 += bv * bv;
    }
    red[(tid & 7) * 32 + ux2] = s2;
    __syncthreads();
    if (tid < 32) {
        float s = 0.f;
#pragma unroll
        for (int k = 0; k < 8; k++) s += red[k * 32 + tid];
        ws[(size_t)bz * SLAB + OFF_N2 + uy * 32 + tid] = s;
    }
}

__global__ __launch_bounds__(256) void k_bnorm_valid(float* __restrict__ ws,
                                                     const float* __restrict__ mask,
                                                     int b0) {
    int t = blockIdx.x * 256 + threadIdx.x;
    int p  = t & (LL - 1);
    int bz = t >> 10;
    int gb = b0 + bz;
    int py = p >> 5, px = p & 31;
    const float* mb = mask + (size_t)gb * HH * WWI;
    const float* n2 = ws + (size_t)bz * SLAB + OFF_N2;
    float s = 0.f, msum = 0.f;
#pragma unroll
    for (int dy = -1; dy <= 1; dy++) {
#pragma unroll
        for (int dx = -1; dx <= 1; dx++) {
            int py2 = py + dy, px2 = px + dx;
            if ((unsigned)py2 < 32u && (unsigned)px2 < 32u) {
                s    += n2[(py2 << 5) | px2];
                msum += mb[(2 * py2) * WWI + 2 * px2];
            }
        }
    }
    ws[(size_t)bz * SLAB + OFF_BNORM + p] = fmaxf(sqrtf(s), 1e-4f);
    ws[(size_t)bz * SLAB + OFF_VALID + p] = (msum == 0.0f) ? 1.0f : 0.0f;
}

__device__ __forceinline__ int halo_idx(int k) {
    if (k < 34) return k;
    if (k < 68) return 1122 + (k - 34);
    if (k < 100) return 34 * (k - 100 + 33);
    return 34 * (k - 132 + 33) + 33;
}

__global__ __launch_bounds__(256) void k_zerohalo(float* __restrict__ ws) {
    int bz = blockIdx.y;
    int t = blockIdx.x * 256 + threadIdx.x;
    if (t >= NHALO) return;
    float* Tp = ws + (size_t)bz * SLAB + OFF_TP;
    if (t < NH1) {
        int R = halo_idx(t / TPD);
        Tp[(size_t)R * TPD + (t % TPD)] = 0.f;
    } else {
        int t2 = t - NH1;
        int ir = t2 / NHROW;
        int R  = 34 * (1 + (ir >> 5)) + 1 + (ir & 31);
        int C  = halo_idx(t2 % NHROW);
        Tp[(size_t)R * TPD + C] = 0.f;
    }
}

// ---- 128x128-tile BK=64 MFMA GEMM core, double-buffered GLDS pipeline ----
// As/Bs each hold TWO 128x64 bf16 buffers (stride 8192 elems). One barrier
// per K-iter: [barrier: drains prev-issued GLDS] [issue GLDS k+1 -> nxt buf]
// [compute k from cur buf]. Load latency hidden by the compute phase.
template<int KTOT>
__device__ __forceinline__ void gemm_core(const __bf16* __restrict__ Ab,
                                          const __bf16* __restrict__ Bb,
                                          int lda, int ldb, int m0, int n0,
                                          __bf16* As, __bf16* Bs,
                                          f32x4 acc[4][4]) {
    int t = threadIdx.x;
    int lane = t & 63, w = t >> 6;
    int rsub = lane >> 3;
    int g8   = ((lane & 7) ^ (rsub & 7)) * 8;
    int lm = lane & 15, kgf = lane >> 4;
    int wm = (w & 1) * 64, wn = (w >> 1) * 64;

    // prologue: issue tile 0 into buf 0
#pragma unroll
    for (int ci = 0; ci < 4; ci++) {
        int rb = ci * 32 + w * 8;
        int r  = rb + rsub;
        GLDS(Ab + (size_t)(m0 + r) * lda + g8, &As[rb * 64]);
        GLDS(Bb + (size_t)(n0 + r) * ldb + g8, &Bs[rb * 64]);
    }

    const int NIT = KTOT / 64;
#pragma unroll 2
    for (int it = 0; it < NIT; it++) {
        __syncthreads();                    // vmcnt(0) drain: tile `it` ready
        int cur = (it & 1) * 8192, nxt = cur ^ 8192;
        if (it + 1 < NIT) {
            int k0 = (it + 1) * 64;
#pragma unroll
            for (int ci = 0; ci < 4; ci++) {
                int rb = ci * 32 + w * 8;
                int r  = rb + rsub;
                GLDS(Ab + (size_t)(m0 + r) * lda + k0 + g8, &As[nxt + rb * 64]);
                GLDS(Bb + (size_t)(n0 + r) * ldb + k0 + g8, &Bs[nxt + rb * 64]);
            }
        }
#pragma unroll
        for (int s2 = 0; s2 < 2; s2++) {
            bf16x8 af[4], bfr[4];
#pragma unroll
            for (int i = 0; i < 4; i++)
                af[i] = *(const bf16x8*)&As[cur + (wm + i * 16 + lm) * 64 + (((s2 * 4 + kgf) ^ (lm & 7)) * 8)];
#pragma unroll
            for (int j = 0; j < 4; j++)
                bfr[j] = *(const bf16x8*)&Bs[cur + (wn + j * 16 + lm) * 64 + (((s2 * 4 + kgf) ^ (lm & 7)) * 8)];
#pragma unroll
            for (int i = 0; i < 4; i++)
#pragma unroll
                for (int j = 0; j < 4; j++)
                    acc[i][j] = __builtin_amdgcn_mfma_f32_16x16x32_bf16(af[i], bfr[j], acc[i][j], 0, 0, 0);
        }
    }
}

// ---- T GEMM (bf16x3 == fp32), padded-4D epilogue; XCD-affinity decode ----
__global__ __launch_bounds__(256) void k_gemm_T_mfma(float* __restrict__ ws, int swz) {
    int bz, m0, n0;
    if (swz) {
        bz = blockIdx.x + 8 * (blockIdx.z & 1);
        m0 = blockIdx.y * 128;
        n0 = (blockIdx.z >> 1) * 128;
    } else {
        bz = blockIdx.z; m0 = blockIdx.y * 128; n0 = blockIdx.x * 128;
    }
    const __bf16* Ab = (const __bf16*)(ws + (size_t)bz * SLAB + OFF_POOL);
    const __bf16* Bb = Ab + 393216;
    float* Tp = ws + (size_t)bz * SLAB + OFF_TP;
    __shared__ __align__(16) __bf16 As[2 * 128 * 64];
    __shared__ __align__(16) __bf16 Bs[2 * 128 * 64];
    f32x4 acc[4][4];
#pragma unroll
    for (int i = 0; i < 4; i++)
#pragma unroll
        for (int j = 0; j < 4; j++) acc[i][j] = (f32x4)0.0f;
    gemm_core<KC>(Ab, Bb, KC, KC, m0, n0, As, Bs, acc);
    int lane = threadIdx.x & 63, w = threadIdx.x >> 6;
    int lm = lane & 15, kgf = lane >> 4;
    int wm = (w & 1) * 64, wn = (w >> 1) * 64;
#pragma unroll
    for (int i = 0; i < 4; i++) {
#pragma unroll
        for (int r = 0; r < 4; r++) {
            int m = m0 + wm + i * 16 + kgf * 4 + r;
            float* dst = Tp + (size_t)(((m >> 5) + 1) * 34 + (m & 31) + 1) * TPD;
#pragma unroll
            for (int j = 0; j < 4; j++) {
                int v = n0 + wn + j * 16 + lm;
                dst[((v >> 5) + 1) * 34 + (v & 31) + 1] = acc[i][j][r];
            }
        }
    }
}

// ---- fused st1+st2 ----
__global__ __launch_bounds__(256) void k_s12(float* __restrict__ ws) {
    int bz = blockIdx.y;
    int i0 = blockIdx.x * 8;
    const float* Tp = ws + (size_t)bz * SLAB + OFF_TP;
    const float* bn = ws + (size_t)bz * SLAB + OFF_BNORM;
    float* S2 = ws + (size_t)bz * SLAB + OFF_S2;
    __shared__ float Dsh[10][1024];
    int tid = threadIdx.x;
    for (int rl = 0; rl < 10; rl++) {
        int r = i0 - 1 + rl;
        if ((unsigned)r >= 1024u) continue;
        float invr = 1.0f / bn[r];
        size_t rbase = (size_t)(((r >> 5) + 1) * 34 + (r & 31) + 1) * TPD;
#pragma unroll
        for (int so = 0; so < 4; so++) {
            int s = so * 256 + tid;
            const float* cb = Tp + rbase + ((s >> 5) + 1) * 34 + (s & 31) + 1;
            float d = 0.f;
#pragma unroll
            for (int dy = -1; dy <= 1; dy++)
#pragma unroll
                for (int dx = -1; dx <= 1; dx++)
                    d += cb[dy * (34 * TPD + 34) + dx * (TPD + 1)];
            Dsh[rl][s] = d * invr;
        }
    }
    __syncthreads();
#pragma unroll
    for (int il = 0; il < 8; il++) {
        int i = i0 + il;
        float* orow = S2 + (size_t)i * LL;
#pragma unroll
        for (int jo = 0; jo < 4; jo++) {
            int j = jo * 256 + tid;
            float acc = 0.f;
#pragma unroll
            for (int k1 = -1; k1 <= 1; k1++) {
                int r = i + k1, s = j + k1;
                if ((unsigned)r < 1024u && (unsigned)s < 1024u)
                    acc += Dsh[il + 1 + k1][s];
            }
            orow[j] = acc;
        }
    }
}

// ---- second diag_fuse (sigma-space) fused with transpose: S3T[q][p] ----
__global__ __launch_bounds__(256) void k_st3t(float* __restrict__ ws) {
    int bz = blockIdx.z;
    const float* ib = ws + (size_t)bz * SLAB + OFF_S2;
    float* ob = ws + (size_t)bz * SLAB + OFF_S3T;
    int p0 = blockIdx.y * 64, q0 = blockIdx.x * 64;
    __shared__ float tile[64][65];
    int t = threadIdx.x;
#pragma unroll
    for (int it = 0; it < 16; it++) {
        int e = it * 256 + t;
        int pl = e >> 6, ql = e & 63;
        int p = p0 + pl, q = q0 + ql;
        int sp = ((p & 31) << 5) | (p >> 5);
        int sq = ((q & 31) << 5) | (q >> 5);
        float acc = 0.f;
#pragma unroll
        for (int k = -1; k <= 1; k++) {
            int tp = sp + k, tq = sq + k;
            if ((unsigned)tp < 1024u && (unsigned)tq < 1024u) {
                int row = ((tp & 31) << 5) | (tp >> 5);
                int col = ((tq & 31) << 5) | (tq >> 5);
                acc += ib[(size_t)row * LL + col];
            }
        }
        tile[pl][ql] = acc;
    }
    __syncthreads();
#pragma unroll
    for (int it = 0; it < 16; it++) {
        int e = it * 256 + t;
        int ql = e >> 6, pl = e & 63;
        ob[(size_t)(q0 + ql) * LL + p0 + pl] = tile[pl][ql];
    }
}

// ---- row softmax on S3T, writes bf16 scoreT[q][p] ----
__global__ __launch_bounds__(256) void k_softmax_bf(float* __restrict__ ws) {
    int bz = blockIdx.z;
    int lane = threadIdx.x & 63;
    int q = blockIdx.x * 4 + (threadIdx.x >> 6);
    const float* row = ws + (size_t)bz * SLAB + OFF_S3T + (size_t)q * LL;
    const float* vb  = ws + (size_t)bz * SLAB + OFF_VALID;
    __bf16* orow = (__bf16*)(ws + (size_t)bz * SLAB + OFF_SCORET) + (size_t)q * LL;

    float4 v[4], vl[4];
#pragma unroll
    for (int i = 0; i < 4; i++) {
        int p = lane * 4 + i * 256;
        float4 s = *(const float4*)(row + p);
        float4 m = *(const float4*)(vb + p);
        v[i] = {s.x * m.x, s.y * m.y, s.z * m.z, s.w * m.w};
        vl[i] = m;
    }
    float mx = -1e30f;
#pragma unroll
    for (int i = 0; i < 4; i++)
        mx = fmaxf(mx, fmaxf(fmaxf(v[i].x, v[i].y), fmaxf(v[i].z, v[i].w)));
#pragma unroll
    for (int k = 1; k < 64; k <<= 1)
        mx = fmaxf(mx, __shfl_xor(mx, k, 64));
    float sum = 0.f;
    float4 e[4];
#pragma unroll
    for (int i = 0; i < 4; i++) {
        e[i].x = __expf(10.f * (v[i].x - mx));
        e[i].y = __expf(10.f * (v[i].y - mx));
        e[i].z = __expf(10.f * (v[i].z - mx));
        e[i].w = __expf(10.f * (v[i].w - mx));
        sum += e[i].x + e[i].y + e[i].z + e[i].w;
    }
#pragma unroll
    for (int k = 1; k < 64; k <<= 1)
        sum += __shfl_xor(sum, k, 64);
    float inv = 1.0f / sum;
#pragma unroll
    for (int i = 0; i < 4; i++) {
        bf16x4 o;
        o[0] = (__bf16)(e[i].x * inv * vl[i].x);
        o[1] = (__bf16)(e[i].y * inv * vl[i].y);
        o[2] = (__bf16)(e[i].z * inv * vl[i].z);
        o[3] = (__bf16)(e[i].w * inv * vl[i].w);
        *(bf16x4*)(orow + lane * 4 + i * 256) = o;
    }
}

// ---- coalesced makeA: block per (channel, batch); LDS image tile ----
__global__ __launch_bounds__(256) void k_makeA(const float* __restrict__ b_o,
                                               float* __restrict__ ws,
                                               int b0) {
    int c = blockIdx.x, bz = blockIdx.y, gb = b0 + bz;
    __shared__ float img[64][65];
    int t = threadIdx.x;
    const float4* src = (const float4*)(b_o + (size_t)(gb * CC + c) * HH * WWI);
#pragma unroll
    for (int it = 0; it < 4; it++) {
        int idx = it * 256 + t;
        float4 v = src[idx];
        int row = idx >> 4, col4 = (idx & 15) * 4;
        img[row][col4] = v.x; img[row][col4 + 1] = v.y;
        img[row][col4 + 2] = v.z; img[row][col4 + 3] = v.w;
    }
    __syncthreads();
    __bf16* Ab = (__bf16*)(ws + (size_t)bz * SLAB + OFF_POOL) + (size_t)c * 9 * LL;
    int py = t >> 3, px4 = (t & 7) * 4;
#pragma unroll
    for (int jy = 0; jy < 3; jy++) {
        int row = 2 * py + jy - 1;
        bool rok = (unsigned)row < 64u;
#pragma unroll
        for (int jx = 0; jx < 3; jx++) {
            bf16x4 o;
#pragma unroll
            for (int e = 0; e < 4; e++) {
                int col = 2 * (px4 + e) + jx - 1;
                float v = (rok && (unsigned)col < 64u) ? img[rok ? row : 0][(unsigned)col < 64u ? col : 0] : 0.f;
                o[e] = (__bf16)v;
            }
            *(bf16x4*)(Ab + (size_t)(jy * 3 + jx) * LL + t * 4) = o;
        }
    }
}

// ---- W[m,q] GEMM; bf16 W stores; XCD-affinity decode ----
__global__ __launch_bounds__(256) void k_gemm_W_mfma(float* __restrict__ ws, int swz) {
    int bz, m0, n0;
    if (swz) {
        bz = blockIdx.x + 8 * (blockIdx.z & 1);
        m0 = blockIdx.y * 128;
        n0 = (blockIdx.z >> 1) * 128;
    } else {
        bz = blockIdx.z; m0 = blockIdx.y * 128; n0 = blockIdx.x * 128;
    }
    const __bf16* Ab = (const __bf16*)(ws + (size_t)bz * SLAB + OFF_POOL);
    const __bf16* Bb = (const __bf16*)(ws + (size_t)bz * SLAB + OFF_SCORET);
    __bf16* Wb = (__bf16*)(ws + (size_t)bz * SLAB + OFF_W);
    __shared__ __align__(16) __bf16 As[2 * 128 * 64];
    __shared__ __align__(16) __bf16 Bs[2 * 128 * 64];
    f32x4 acc[4][4];
#pragma unroll
    for (int i = 0; i < 4; i++)
#pragma unroll
        for (int j = 0; j < 4; j++) acc[i][j] = (f32x4)0.0f;
    gemm_core<LL>(Ab, Bb, LL, LL, m0, n0, As, Bs, acc);
    int lane = threadIdx.x & 63, w = threadIdx.x >> 6;
    int lm = lane & 15, kgf = lane >> 4;
    int wm = (w & 1) * 64, wn = (w >> 1) * 64;
#pragma unroll
    for (int i = 0; i < 4; i++) {
#pragma unroll
        for (int r = 0; r < 4; r++) {
            int m = m0 + wm + i * 16 + kgf * 4 + r;
            __bf16* dst = Wb + (size_t)m * LL + n0 + wn + lm;
#pragma unroll
            for (int j = 0; j < 4; j++)
                dst[j * 16] = (__bf16)acc[i][j][r];
        }
    }
}

// ---- gather: out[c,oy,ox] = 0.25 * sum of <=4 bf16 W taps ----
__global__ __launch_bounds__(256) void k_gather(const float* __restrict__ ws,
                                                float* __restrict__ outp,
                                                int b0) {
    int t = blockIdx.x * 256 + threadIdx.x;
    int ox = t & 63, oy = (t >> 6) & 63, c = (t >> 12) & 127, bz = t >> 19;
    const __bf16* Wb = (const __bf16*)(ws + (size_t)bz * SLAB + OFF_W);
    int qyA = (oy + 1) >> 1;
    int jyA = (oy & 1) ? 0 : 1;
    int vA  = (qyA < 32);
    int qyB = (oy - 1) >> 1;
    int vB  = (oy & 1);
    int qxA = (ox + 1) >> 1;
    int jxA = (ox & 1) ? 0 : 1;
    int uA  = (qxA < 32);
    int qxB = (ox - 1) >> 1;
    int uB  = (ox & 1);
    const __bf16* base = Wb + (size_t)c * 9 * LL;
    float s = 0.f;
    if (vA && uA) s += (float)base[(size_t)(jyA * 3 + jxA) * LL + qyA * 32 + qxA];
    if (vA && uB) s += (float)base[(size_t)(jyA * 3 + 2)   * LL + qyA * 32 + qxB];
    if (vB && uA) s += (float)base[(size_t)(2 * 3 + jxA)   * LL + qyB * 32 + qxA];
    if (vB && uB) s += (float)base[(size_t)(2 * 3 + 2)     * LL + qyB * 32 + qxB];
    outp[((size_t)((b0 + bz) * CC + c) * HH + oy) * WWI + ox] = 0.25f * s;
}

extern "C" void kernel_launch(void* const* d_in, const int* in_sizes, int n_in,
                              void* d_out, int out_size, void* d_ws, size_t ws_size,
                              hipStream_t stream) {
    (void)in_sizes; (void)n_in; (void)out_size;
    const float* f_o  = (const float*)d_in[0];
    const float* b_o  = (const float*)d_in[1];
    const float* mask = (const float*)d_in[2];
    float* out = (float*)d_out;

    int G = (int)(ws_size / (SLAB * sizeof(float)));   // ~11.4 MB per batch slab
    if (G < 1) G = 1;
    if (G > NB) G = NB;
    float* ws = (float*)d_ws;

    for (int b0 = 0; b0 < NB; b0 += G) {
        int Gc = NB - b0 < G ? NB - b0 : G;
        int swz = (Gc == 16) ? 1 : 0;
        k_prep<<<dim3(32, Gc), 256, 0, stream>>>(f_o, b_o, ws, b0);
        k_bnorm_valid<<<dim3(Gc * 4), 256, 0, stream>>>(ws, mask, b0);
        k_zerohalo<<<dim3((NHALO + 255) / 256, Gc), 256, 0, stream>>>(ws);
        k_gemm_T_mfma<<<dim3(8, 8, Gc), 256, 0, stream>>>(ws, swz);
        k_s12<<<dim3(128, Gc), 256, 0, stream>>>(ws);
        k_st3t<<<dim3(16, 16, Gc), 256, 0, stream>>>(ws);
        k_softmax_bf<<<dim3(256, 1, Gc), 256, 0, stream>>>(ws);
        k_makeA<<<dim3(CC, Gc), 256, 0, stream>>>(b_o, ws, b0);
        k_gemm_W_mfma<<<dim3(8, 9, Gc), 256, 0, stream>>>(ws, swz);
        k_gather<<<dim3(Gc * 2048), 256, 0, stream>>>(ws, out, b0);
    }
}